// Round 2
// baseline (657.475 us; speedup 1.0000x reference)
//
#include <hip/hip_runtime.h>
#include <cstdint>
#include <cstddef>

#define DEV __device__ __forceinline__

typedef _Float16 f16;
typedef __attribute__((ext_vector_type(8))) _Float16 f16x8;
typedef __attribute__((ext_vector_type(4))) float f32x4;

DEV unsigned short f2h(float f) {
  f16 h = (f16)f;
  return __builtin_bit_cast(unsigned short, h);
}

DEV void async_ld16(const void* g, void* l) {
  __builtin_amdgcn_global_load_lds(
      (__attribute__((address_space(1))) unsigned int*)(uintptr_t)g,
      (__attribute__((address_space(3))) unsigned int*)(uint32_t)(uintptr_t)l,
      16, 0, 0);
}

#define MFMA16(d, a, b_) (d) = __builtin_amdgcn_mfma_f32_16x16x32_f16((a), (b_), (d), 0, 0, 0)

// ---------------------------------------------------------------------------
// gemm256: C[M x N] = A[M x K] * B[N x K]^T  (K-contiguous, f16-as-ushort)
// 256x256 tile, BK=64, 8 waves (2Mx4N), 8-phase pipeline — IDENTICAL schedule
// to qk256 below (verified R1): per phase {ds_read subtile | stage ONE 16KB
// half-tile | s_barrier | lgkmcnt(0) | 16 MFMA (setprio) | s_barrier},
// vmcnt(6) once per K-tile, stage depth 7 halves, tail stages wrap k.
// EPI: 0 = fp16 store (+bias/relu), 2 = fp32 atomicAdd.
// ALPHA: stage alphaT[(K/128) x 256] slice into a 4KB LDS annex at 128KiB,
// scale av0 at phase0 / av1 at phase2 (reads covered by the phase lgkmcnt(0)).
// Grid 1D = nt*mt*sl; K param = per-slice depth; zb = slice index.
// ---------------------------------------------------------------------------
template <int EPI, bool RELU, bool HASBIAS, bool ALPHA>
__global__ __launch_bounds__(512, 2) void gemm256(
    const unsigned short* __restrict__ A, const unsigned short* __restrict__ B,
    void* __restrict__ Cp, const float* __restrict__ bias,
    const unsigned short* __restrict__ alp, int Mtot,
    int K, int lda, int ldb, int ldc, int nt, int mt) {
  extern __shared__ char smem[];
  const int NT = K >> 6;

  const int b = blockIdx.x;
  const int nb = b % nt;
  const int t = b / nt;
  const int mb = t % mt;
  const int zb = t / mt;
  const int bm = mb << 8, bn = nb << 8;
  const unsigned koff = (unsigned)zb * (unsigned)K;

  const int tid = threadIdx.x;
  const int wave = tid >> 6, lane = tid & 63;
  const int wr = wave >> 2, wc = wave & 3;   // wave grid 2 x 4
  const int mr = lane & 15, quad = lane >> 4;

  const int slot = tid & 7, rr = tid >> 3;
  const int ce = (slot ^ (rr & 7)) << 3;     // inverse-swizzled global col (x8 f16)

  f32x4 acc[8][4] = {};
  f16x8 av0[4][2], av1[4][2], bv0[2][2], bv1[2][2];
  const f16* alb = (const f16*)(smem + 131072);

  if (ALPHA) {
    // stage alphaT slice: (K/128) tiles x 256 rows fp16 -> annex at 128KiB
    const int ntl = K >> 7;
    const unsigned short* g0 = alp + (size_t)(zb * ntl) * Mtot + bm;
    uint4* s = (uint4*)(smem + 131072);
    const int nu4 = (ntl << 5);              // (ntl*256)/8
    for (int idx = tid; idx < nu4; idx += 512) {
      const int tt = idx >> 5;
      const int ru = (idx & 31) << 3;
      s[idx] = *(const uint4*)(g0 + (size_t)tt * Mtot + ru);
    }
  }

  auto stA = [&](int h, int Ts) {
    const int t_ = Ts >= NT ? Ts - NT : Ts;  // tail wrap: keep vmcnt ledger
    const unsigned kk = koff + (unsigned)(t_ << 6);
    char* l = smem + ((Ts & 1) << 16) + h * 16384 + wave * 1024;
#pragma unroll
    for (int p = 0; p < 2; ++p) {
      const unsigned off = (unsigned)(bm + p * 128 + h * 64 + rr) * (unsigned)lda + kk + ce;
      async_ld16(A + off, l + p * 8192);
    }
  };
  auto stB = [&](int h, int Ts) {
    const int t_ = Ts >= NT ? Ts - NT : Ts;
    const unsigned kk = koff + (unsigned)(t_ << 6);
    char* l = smem + ((Ts & 1) << 16) + 32768 + h * 16384 + wave * 1024;
#pragma unroll
    for (int p = 0; p < 2; ++p) {
      const unsigned off =
          (unsigned)(bn + p * 128 + (rr >> 5) * 64 + h * 32 + (rr & 31)) * (unsigned)ldb + kk + ce;
      async_ld16(B + off, l + p * 8192);
    }
  };
  auto rdA = [&](int bufc, int i, int ks) {
    const int r = wr * 64 + (i & 3) * 16 + mr;
    return *(const f16x8*)(smem + bufc + (i >> 2) * 16384 + r * 128 +
                           ((((ks << 2) | quad) ^ (mr & 7)) << 4));
  };
  auto rdB = [&](int bufc, int j, int ks) {
    const int r = wc * 32 + (j & 1) * 16 + mr;
    return *(const f16x8*)(smem + bufc + 32768 + (j >> 1) * 16384 + r * 128 +
                           ((((ks << 2) | quad) ^ (mr & 7)) << 4));
  };

  // prologue: stage H0..H6, wait for the 8 oldest (tile0's 4 halves)
  stA(0, 0); stB(0, 0); stA(1, 0); stB(1, 0);
  stA(0, 1); stB(0, 1); stA(1, 1);
  if (ALPHA) asm volatile("s_waitcnt lgkmcnt(0)" ::: "memory");  // alpha ds_writes
  asm volatile("s_waitcnt vmcnt(6)" ::: "memory");
  __builtin_amdgcn_s_barrier();

  for (int T = 0; T < NT; ++T) {
    const int bufc = (T & 1) << 16;
    f16 a0_[4], a1_[4];
    // ---- phase 0: read A-half0 (+alpha) | stage B1(T+1) | MFMA prev (4..7 x 2..3)
#pragma unroll
    for (int i = 0; i < 4; ++i) { av0[i][0] = rdA(bufc, i, 0); av0[i][1] = rdA(bufc, i, 1); }
    if (ALPHA) {
#pragma unroll
      for (int i = 0; i < 4; ++i) a0_[i] = alb[(T >> 1) * 256 + wr * 128 + i * 16 + mr];
    }
    stB(1, T + 1);
    __builtin_amdgcn_s_barrier();
    asm volatile("s_waitcnt lgkmcnt(0)" ::: "memory");
    __builtin_amdgcn_sched_barrier(0);
    if (ALPHA) {
#pragma unroll
      for (int i = 0; i < 4; ++i) { av0[i][0] = av0[i][0] * a0_[i]; av0[i][1] = av0[i][1] * a0_[i]; }
    }
    if (T) {
      __builtin_amdgcn_s_setprio(1);
#pragma unroll
      for (int i = 0; i < 4; ++i)
#pragma unroll
        for (int j = 0; j < 2; ++j) {
          MFMA16(acc[4 + i][2 + j], av1[i][0], bv1[j][0]);
          MFMA16(acc[4 + i][2 + j], av1[i][1], bv1[j][1]);
        }
      __builtin_amdgcn_s_setprio(0);
    }
    __builtin_amdgcn_s_barrier();
    // ---- phase 1: read B-half0 | stage A0(T+2) | MFMA (0..3 x 0..1)
#pragma unroll
    for (int j = 0; j < 2; ++j) { bv0[j][0] = rdB(bufc, j, 0); bv0[j][1] = rdB(bufc, j, 1); }
    stA(0, T + 2);
    __builtin_amdgcn_s_barrier();
    asm volatile("s_waitcnt lgkmcnt(0)" ::: "memory");
    __builtin_amdgcn_sched_barrier(0);
    __builtin_amdgcn_s_setprio(1);
#pragma unroll
    for (int i = 0; i < 4; ++i)
#pragma unroll
      for (int j = 0; j < 2; ++j) {
        MFMA16(acc[i][j], av0[i][0], bv0[j][0]);
        MFMA16(acc[i][j], av0[i][1], bv0[j][1]);
      }
    __builtin_amdgcn_s_setprio(0);
    __builtin_amdgcn_s_barrier();
    // ---- phase 2: read A-half1 (+alpha) | stage B0(T+2) | MFMA (4..7 x 0..1)
#pragma unroll
    for (int i = 0; i < 4; ++i) { av1[i][0] = rdA(bufc, 4 + i, 0); av1[i][1] = rdA(bufc, 4 + i, 1); }
    if (ALPHA) {
#pragma unroll
      for (int i = 0; i < 4; ++i) a1_[i] = alb[(T >> 1) * 256 + wr * 128 + 64 + i * 16 + mr];
    }
    stB(0, T + 2);
    __builtin_amdgcn_s_barrier();
    asm volatile("s_waitcnt lgkmcnt(0)" ::: "memory");
    __builtin_amdgcn_sched_barrier(0);
    if (ALPHA) {
#pragma unroll
      for (int i = 0; i < 4; ++i) { av1[i][0] = av1[i][0] * a1_[i]; av1[i][1] = av1[i][1] * a1_[i]; }
    }
    __builtin_amdgcn_s_setprio(1);
#pragma unroll
    for (int i = 0; i < 4; ++i)
#pragma unroll
      for (int j = 0; j < 2; ++j) {
        MFMA16(acc[4 + i][j], av1[i][0], bv0[j][0]);
        MFMA16(acc[4 + i][j], av1[i][1], bv0[j][1]);
      }
    __builtin_amdgcn_s_setprio(0);
    __builtin_amdgcn_s_barrier();
    // ---- phase 3: read B-half1 | stage A1(T+2) | MFMA (0..3 x 2..3) | vmcnt(6)
#pragma unroll
    for (int j = 0; j < 2; ++j) { bv1[j][0] = rdB(bufc, 2 + j, 0); bv1[j][1] = rdB(bufc, 2 + j, 1); }
    stA(1, T + 2);
    __builtin_amdgcn_s_barrier();
    asm volatile("s_waitcnt lgkmcnt(0)" ::: "memory");
    __builtin_amdgcn_sched_barrier(0);
    __builtin_amdgcn_s_setprio(1);
#pragma unroll
    for (int i = 0; i < 4; ++i)
#pragma unroll
      for (int j = 0; j < 2; ++j) {
        MFMA16(acc[i][2 + j], av0[i][0], bv1[j][0]);
        MFMA16(acc[i][2 + j], av0[i][1], bv1[j][1]);
      }
    __builtin_amdgcn_s_setprio(0);
    asm volatile("s_waitcnt vmcnt(6)" ::: "memory");
    __builtin_amdgcn_s_barrier();
  }
  // final cross-tile cluster: (4..7 x 2..3) of tile NT-1
  __builtin_amdgcn_s_setprio(1);
#pragma unroll
  for (int i = 0; i < 4; ++i)
#pragma unroll
    for (int j = 0; j < 2; ++j) {
      MFMA16(acc[4 + i][2 + j], av1[i][0], bv1[j][0]);
      MFMA16(acc[4 + i][2 + j], av1[i][1], bv1[j][1]);
    }
  __builtin_amdgcn_s_setprio(0);
  asm volatile("s_waitcnt vmcnt(0)" ::: "memory");
  __builtin_amdgcn_s_barrier();

  // ---- epilogue ---------------------------------------------------------
#pragma unroll
  for (int i = 0; i < 8; ++i) {
#pragma unroll
    for (int j = 0; j < 4; ++j) {
      const int col = bn + wc * 64 + j * 16 + mr;
      float bb = 0.f;
      if (HASBIAS) bb = bias[col];
#pragma unroll
      for (int r = 0; r < 4; ++r) {
        const int row = bm + wr * 128 + i * 16 + quad * 4 + r;
        float v = acc[i][j][r];
        if (HASBIAS) v += bb;
        if (RELU) v = fmaxf(v, 0.f);
        if (EPI == 2)
          atomicAdd(&((float*)Cp)[(size_t)row * ldc + col], v);
        else
          ((unsigned short*)Cp)[(size_t)row * ldc + col] = f2h(v);
      }
    }
  }
}

// ---------------------------------------------------------------------------
// qk256: S = Q·K^T with fused exp + per-(row,128-col-half) m/l stats.
// (verified R1 — unchanged)
// ---------------------------------------------------------------------------
__global__ __launch_bounds__(512, 2) void qk256(
    const unsigned short* __restrict__ A, const unsigned short* __restrict__ B,
    unsigned short* __restrict__ P, float* __restrict__ stm,
    float* __restrict__ stl, int M, int K, int lda, int ldb, int ldc) {
  extern __shared__ char smem[];
  const int NT = K >> 6;

  const int b = blockIdx.x;
  const int xcd = b & 7, c = b >> 3;
  const int mb = c & 31, nb = (xcd << 2) | (c >> 5);
  const int bm = mb << 8, bn = nb << 8;

  const int tid = threadIdx.x;
  const int wave = tid >> 6, lane = tid & 63;
  const int wr = wave >> 2, wc = wave & 3;
  const int mr = lane & 15, quad = lane >> 4;

  const int slot = tid & 7, rr = tid >> 3;
  const int ce = (slot ^ (rr & 7)) << 3;

  f32x4 acc[8][4] = {};
  f16x8 av0[4][2], av1[4][2], bv0[2][2], bv1[2][2];

  auto stA = [&](int h, int Ts) {
    const int t = Ts >= NT ? Ts - NT : Ts;
    const int kk = t << 6;
    char* l = smem + ((Ts & 1) << 16) + h * 16384 + wave * 1024;
#pragma unroll
    for (int p = 0; p < 2; ++p) {
      const unsigned off = (unsigned)(bm + p * 128 + h * 64 + rr) * (unsigned)lda + kk + ce;
      async_ld16(A + off, l + p * 8192);
    }
  };
  auto stB = [&](int h, int Ts) {
    const int t = Ts >= NT ? Ts - NT : Ts;
    const int kk = t << 6;
    char* l = smem + ((Ts & 1) << 16) + 32768 + h * 16384 + wave * 1024;
#pragma unroll
    for (int p = 0; p < 2; ++p) {
      const unsigned off =
          (unsigned)(bn + p * 128 + (rr >> 5) * 64 + h * 32 + (rr & 31)) * (unsigned)ldb + kk + ce;
      async_ld16(B + off, l + p * 8192);
    }
  };
  auto rdA = [&](int bufc, int i, int ks) {
    const int r = wr * 64 + (i & 3) * 16 + mr;
    return *(const f16x8*)(smem + bufc + (i >> 2) * 16384 + r * 128 +
                           ((((ks << 2) | quad) ^ (mr & 7)) << 4));
  };
  auto rdB = [&](int bufc, int j, int ks) {
    const int r = wc * 32 + (j & 1) * 16 + mr;
    return *(const f16x8*)(smem + bufc + 32768 + (j >> 1) * 16384 + r * 128 +
                           ((((ks << 2) | quad) ^ (mr & 7)) << 4));
  };

  stA(0, 0); stB(0, 0); stA(1, 0); stB(1, 0);
  stA(0, 1); stB(0, 1); stA(1, 1);
  asm volatile("s_waitcnt vmcnt(6)" ::: "memory");
  __builtin_amdgcn_s_barrier();

  for (int T = 0; T < NT; ++T) {
    const int bufc = (T & 1) << 16;
#pragma unroll
    for (int i = 0; i < 4; ++i) { av0[i][0] = rdA(bufc, i, 0); av0[i][1] = rdA(bufc, i, 1); }
    stB(1, T + 1);
    __builtin_amdgcn_s_barrier();
    asm volatile("s_waitcnt lgkmcnt(0)" ::: "memory");
    __builtin_amdgcn_sched_barrier(0);
    if (T) {
      __builtin_amdgcn_s_setprio(1);
#pragma unroll
      for (int i = 0; i < 4; ++i)
#pragma unroll
        for (int j = 0; j < 2; ++j) {
          MFMA16(acc[4 + i][2 + j], av1[i][0], bv1[j][0]);
          MFMA16(acc[4 + i][2 + j], av1[i][1], bv1[j][1]);
        }
      __builtin_amdgcn_s_setprio(0);
    }
    __builtin_amdgcn_s_barrier();
#pragma unroll
    for (int j = 0; j < 2; ++j) { bv0[j][0] = rdB(bufc, j, 0); bv0[j][1] = rdB(bufc, j, 1); }
    stA(0, T + 2);
    __builtin_amdgcn_s_barrier();
    asm volatile("s_waitcnt lgkmcnt(0)" ::: "memory");
    __builtin_amdgcn_sched_barrier(0);
    __builtin_amdgcn_s_setprio(1);
#pragma unroll
    for (int i = 0; i < 4; ++i)
#pragma unroll
      for (int j = 0; j < 2; ++j) {
        MFMA16(acc[i][j], av0[i][0], bv0[j][0]);
        MFMA16(acc[i][j], av0[i][1], bv0[j][1]);
      }
    __builtin_amdgcn_s_setprio(0);
    __builtin_amdgcn_s_barrier();
#pragma unroll
    for (int i = 0; i < 4; ++i) { av1[i][0] = rdA(bufc, 4 + i, 0); av1[i][1] = rdA(bufc, 4 + i, 1); }
    stB(0, T + 2);
    __builtin_amdgcn_s_barrier();
    asm volatile("s_waitcnt lgkmcnt(0)" ::: "memory");
    __builtin_amdgcn_sched_barrier(0);
    __builtin_amdgcn_s_setprio(1);
#pragma unroll
    for (int i = 0; i < 4; ++i)
#pragma unroll
      for (int j = 0; j < 2; ++j) {
        MFMA16(acc[4 + i][j], av1[i][0], bv0[j][0]);
        MFMA16(acc[4 + i][j], av1[i][1], bv0[j][1]);
      }
    __builtin_amdgcn_s_setprio(0);
    __builtin_amdgcn_s_barrier();
#pragma unroll
    for (int j = 0; j < 2; ++j) { bv1[j][0] = rdB(bufc, 2 + j, 0); bv1[j][1] = rdB(bufc, 2 + j, 1); }
    stA(1, T + 2);
    __builtin_amdgcn_s_barrier();
    asm volatile("s_waitcnt lgkmcnt(0)" ::: "memory");
    __builtin_amdgcn_sched_barrier(0);
    __builtin_amdgcn_s_setprio(1);
#pragma unroll
    for (int i = 0; i < 4; ++i)
#pragma unroll
      for (int j = 0; j < 2; ++j) {
        MFMA16(acc[i][2 + j], av0[i][0], bv1[j][0]);
        MFMA16(acc[i][2 + j], av0[i][1], bv1[j][1]);
      }
    __builtin_amdgcn_s_setprio(0);
    asm volatile("s_waitcnt vmcnt(6)" ::: "memory");
    __builtin_amdgcn_s_barrier();
  }
  __builtin_amdgcn_s_setprio(1);
#pragma unroll
  for (int i = 0; i < 4; ++i)
#pragma unroll
    for (int j = 0; j < 2; ++j) {
      MFMA16(acc[4 + i][2 + j], av1[i][0], bv1[j][0]);
      MFMA16(acc[4 + i][2 + j], av1[i][1], bv1[j][1]);
    }
  __builtin_amdgcn_s_setprio(0);
  asm volatile("s_waitcnt vmcnt(0)" ::: "memory");
  __builtin_amdgcn_s_barrier();

  float* sred = (float*)smem;
  float* ssum = (float*)(smem + 4096);
  const int hc = wc >> 1;
  float Mh[8][4];

#pragma unroll
  for (int i = 0; i < 8; ++i)
#pragma unroll
    for (int r = 0; r < 4; ++r) {
      float m = acc[i][0][r];
#pragma unroll
      for (int j = 1; j < 4; ++j) m = fmaxf(m, acc[i][j][r]);
      m = fmaxf(m, __shfl_xor(m, 1));
      m = fmaxf(m, __shfl_xor(m, 2));
      m = fmaxf(m, __shfl_xor(m, 4));
      m = fmaxf(m, __shfl_xor(m, 8));
      if (mr == 0) sred[(wr * 128 + i * 16 + quad * 4 + r) * 4 + wc] = m;
    }
  __syncthreads();
#pragma unroll
  for (int i = 0; i < 8; ++i)
#pragma unroll
    for (int r = 0; r < 4; ++r) {
      const int row_l = wr * 128 + i * 16 + quad * 4 + r;
      Mh[i][r] = fmaxf(sred[row_l * 4 + 2 * hc], sred[row_l * 4 + 2 * hc + 1]);
    }
#pragma unroll
  for (int i = 0; i < 8; ++i)
#pragma unroll
    for (int r = 0; r < 4; ++r) {
      const int row_l = wr * 128 + i * 16 + quad * 4 + r;
      float l = 0.f;
#pragma unroll
      for (int j = 0; j < 4; ++j) {
        const float e = __expf(acc[i][j][r] - Mh[i][r]);
        P[(size_t)(bm + row_l) * ldc + (bn + wc * 64 + j * 16 + mr)] = f2h(e);
        l += e;
      }
      l += __shfl_xor(l, 1);
      l += __shfl_xor(l, 2);
      l += __shfl_xor(l, 4);
      l += __shfl_xor(l, 8);
      if (mr == 0) ssum[row_l * 4 + wc] = l;
    }
  __syncthreads();
  if ((wc & 1) == 0 && mr == 0) {
#pragma unroll
    for (int i = 0; i < 8; ++i)
#pragma unroll
      for (int r = 0; r < 4; ++r) {
        const int row_l = wr * 128 + i * 16 + quad * 4 + r;
        const int tile = nb * 2 + hc;
        stm[(size_t)tile * M + bm + row_l] = Mh[i][r];
        stl[(size_t)tile * M + bm + row_l] =
            ssum[row_l * 4 + 2 * hc] + ssum[row_l * 4 + 2 * hc + 1];
      }
  }
}

// per-row combine: M = max_t m_t, L = sum_t l_t*exp(m_t-M)
__global__ __launch_bounds__(256) void combine_alpha(
    const float* __restrict__ stm, const float* __restrict__ stl,
    unsigned short* __restrict__ alp, int ntile, int Mtot) {
  const int row = blockIdx.x * 4 + (threadIdx.x >> 6);
  const int t = threadIdx.x & 63;
  float m = (t < ntile) ? stm[(size_t)t * Mtot + row] : -1e30f;
  float M = m;
#pragma unroll
  for (int o = 1; o < 64; o <<= 1) M = fmaxf(M, __shfl_xor(M, o));
  float l = (t < ntile) ? stl[(size_t)t * Mtot + row] : 0.f;
  float c = l * __expf(m - M);
#pragma unroll
  for (int o = 1; o < 64; o <<= 1) c += __shfl_xor(c, o);
  if (t < ntile) alp[(size_t)t * Mtot + row] = f2h(__expf(m - M) / c);
}

__global__ __launch_bounds__(256) void cvt_f16(const float* __restrict__ in,
                                               unsigned short* __restrict__ out, int n) {
  int i = blockIdx.x * 256 + threadIdx.x;
  if (i < n) out[i] = f2h(in[i]);
}

__global__ __launch_bounds__(256) void bias_fill(float* __restrict__ out,
                                                 const float* __restrict__ b, int d) {
  int i = blockIdx.x * 256 + threadIdx.x;
  out[i] = b[i % d];
}

// V [8192 x 768] fp32 -> vT [768 x 8192] fp16
__global__ __launch_bounds__(256) void vt_kernel(const float* __restrict__ V,
                                                 unsigned short* __restrict__ vT) {
  __shared__ float t[32][33];
  const int bx = blockIdx.x, by = blockIdx.y;
  const int x = threadIdx.x, y = threadIdx.y;
#pragma unroll
  for (int r = 0; r < 4; ++r)
    t[y + r * 8][x] = V[(size_t)(by * 32 + y + r * 8) * 768 + bx * 32 + x];
  __syncthreads();
#pragma unroll
  for (int r = 0; r < 4; ++r)
    vT[(size_t)(bx * 32 + y + r * 8) * 8192 + by * 32 + x] = f2h(t[x][y + r * 8]);
}

// ---------------------------------------------------------------------------
extern "C" void kernel_launch(void* const* d_in, const int* in_sizes, int n_in,
                              void* d_out, int out_size, void* d_ws, size_t ws_size,
                              hipStream_t stream) {
  const int N = 8192, D = 768, DFF = 2048;
  const float* Q  = (const float*)d_in[0];
  const float* Km = (const float*)d_in[1];
  const float* V  = (const float*)d_in[2];
  const float* W1 = (const float*)d_in[3];
  const float* b1 = (const float*)d_in[4];
  const float* W2 = (const float*)d_in[5];
  const float* b2 = (const float*)d_in[6];

  char* w = (char*)d_ws;
  size_t off = 0;
  auto take = [&](size_t bytes) { void* p = w + off; off += bytes; return p; };
  unsigned short* qh   = (unsigned short*)take((size_t)N * D * 2);
  unsigned short* kh   = (unsigned short*)take((size_t)N * D * 2);
  unsigned short* vT   = (unsigned short*)take((size_t)N * D * 2);
  unsigned short* ctx16= (unsigned short*)take((size_t)N * D * 2);
  float*          ctx32= (float*)take((size_t)N * D * 4);
  unsigned short* hb   = (unsigned short*)take((size_t)N * DFF * 2);
  unsigned short* w1h  = (unsigned short*)take((size_t)DFF * D * 2);
  unsigned short* w2h  = (unsigned short*)take((size_t)D * DFF * 2);
  float*          stm  = (float*)take((size_t)64 * N * 4);
  float*          stl  = (float*)take((size_t)64 * N * 4);
  unsigned short* alp  = (unsigned short*)take((size_t)64 * N * 2);  // [tile][row]
  unsigned short* Pp   = (unsigned short*)take((size_t)N * N * 2);   // P' fp16, 128 MB
  (void)ws_size;

  cvt_f16<<<(N * D) / 256, 256, 0, stream>>>(Q, qh, N * D);
  cvt_f16<<<(N * D) / 256, 256, 0, stream>>>(Km, kh, N * D);
  vt_kernel<<<dim3(D / 32, N / 32), dim3(32, 8), 0, stream>>>(V, vT);
  cvt_f16<<<(DFF * D) / 256, 256, 0, stream>>>(W1, w1h, DFF * D);
  cvt_f16<<<(D * DFF) / 256, 256, 0, stream>>>(W2, w2h, D * DFF);
  hipMemsetAsync(ctx32, 0, (size_t)N * D * 4, stream);
  bias_fill<<<(N * D) / 256, 256, 0, stream>>>((float*)d_out, b2, D);

  {  // QK^T 256^2 8-phase with fused exp + per-(row,128-tile) stats
    hipFuncSetAttribute((const void*)qk256,
                        hipFuncAttributeMaxDynamicSharedMemorySize, 131072);
    qk256<<<(N / 256) * (N / 256), 512, 131072, stream>>>(
        qh, kh, Pp, stm, stl, N, D, D, D, N);
  }
  combine_alpha<<<N / 4, 256, 0, stream>>>(stm, stl, alp, 64, N);

  {  // ctx32 += (alphaT .* P') . V  — 256^2 8-phase, split-K sl=8, fp32 atomics
    const int nt = D / 256, mt = N / 256, sl = 8;   // 3 x 32 x 8 = 768 blocks
    const int smem_sz = 131072 + ((N / sl) >> 7) * 256 * 2;  // +4KB alpha annex
    hipFuncSetAttribute((const void*)gemm256<2, false, false, true>,
                        hipFuncAttributeMaxDynamicSharedMemorySize, smem_sz);
    gemm256<2, false, false, true><<<nt * mt * sl, 512, smem_sz, stream>>>(
        Pp, vT, ctx32, nullptr, alp, N,
        N / sl, N, N, D, nt, mt);
  }
  cvt_f16<<<(N * D) / 256, 256, 0, stream>>>(ctx32, ctx16, N * D);

  {  // h = relu(ctx . W1^T + b1)  fp16 — 256^2 8-phase, grid = 256 blocks
    const int nt = DFF / 256, mt = N / 256;
    hipFuncSetAttribute((const void*)gemm256<0, true, true, false>,
                        hipFuncAttributeMaxDynamicSharedMemorySize, 131072);
    gemm256<0, true, true, false><<<nt * mt, 512, 131072, stream>>>(
        ctx16, w1h, hb, b1, nullptr, N,
        D, D, D, DFF, nt, mt);
  }
  {  // out += h . W2^T  (bias pre-filled) — 256^2 8-phase, sl=2, fp32 atomics
    const int nt = D / 256, mt = N / 256, sl = 2;
    hipFuncSetAttribute((const void*)gemm256<2, false, false, false>,
                        hipFuncAttributeMaxDynamicSharedMemorySize, 131072);
    gemm256<2, false, false, false><<<nt * mt * sl, 512, 131072, stream>>>(
        hb, w2h, (float*)d_out, nullptr, nullptr, N,
        DFF / sl, DFF, DFF, D, nt, mt);
  }
}

// Round 3
// 576.022 us; speedup vs baseline: 1.1414x; 1.1414x over previous
//
#include <hip/hip_runtime.h>
#include <cstdint>
#include <cstddef>

#define DEV __device__ __forceinline__

typedef _Float16 f16;
typedef __attribute__((ext_vector_type(8))) _Float16 f16x8;
typedef __attribute__((ext_vector_type(4))) float f32x4;

DEV unsigned short f2h(float f) {
  f16 h = (f16)f;
  return __builtin_bit_cast(unsigned short, h);
}

DEV void async_ld16(const void* g, void* l) {
  __builtin_amdgcn_global_load_lds(
      (__attribute__((address_space(1))) unsigned int*)(uintptr_t)g,
      (__attribute__((address_space(3))) unsigned int*)(uint32_t)(uintptr_t)l,
      16, 0, 0);
}

#define MFMA16(d, a, b_) (d) = __builtin_amdgcn_mfma_f32_16x16x32_f16((a), (b_), (d), 0, 0, 0)

// ---------------------------------------------------------------------------
// gemm256: C[M x N] = A[M x K] * B[N x K]^T  (K-contiguous, f16-as-ushort)
// 256x256 tile, BK=64, 8 waves (2Mx4N), 8-phase pipeline (verified R1/R2).
// EPI: 0 = fp16 store (+bias/relu), 2 = fp32 atomicAdd.
// ALPHA: stage alphaT[(K/128) x 256] slice into LDS annex at 128KiB,
// scale av0 at phase0 / av1 at phase2.
// XCD: per-XCD nb-inner placement — the nt blocks sharing one A-panel are
// co-resident on one XCD (HW maps linear id round-robin over 8 XCDs), so the
// A-panel is HBM-fetched once and re-read from XCD L2. Requires mt%8==0 and
// grid == nt*mt*sl. R2 post-mortem: without this, PV's cold 128MB A stream
// needs ~7.7TB/s (3x re-read) > 6.3 achievable -> 17% MfmaUtil.
// ---------------------------------------------------------------------------
template <int EPI, bool RELU, bool HASBIAS, bool ALPHA, bool XCD>
__global__ __launch_bounds__(512, 2) void gemm256(
    const unsigned short* __restrict__ A, const unsigned short* __restrict__ B,
    void* __restrict__ Cp, const float* __restrict__ bias,
    const unsigned short* __restrict__ alp, int Mtot,
    int K, int lda, int ldb, int ldc, int nt, int mt, int sl) {
  extern __shared__ char smem[];
  const int NT = K >> 6;

  int mb, nb, zb;
  {
    const int b = blockIdx.x;
    if (XCD) {
      const int xcd = b & 7, q = b >> 3;
      nb = q % nt;
      const int rest = q / nt;
      zb = rest % sl;
      mb = xcd * (mt >> 3) + rest / sl;
    } else {
      nb = b % nt;
      const int t = b / nt;
      mb = t % mt;
      zb = t / mt;
    }
  }
  const int bm = mb << 8, bn = nb << 8;
  const unsigned koff = (unsigned)zb * (unsigned)K;

  const int tid = threadIdx.x;
  const int wave = tid >> 6, lane = tid & 63;
  const int wr = wave >> 2, wc = wave & 3;   // wave grid 2 x 4
  const int mr = lane & 15, quad = lane >> 4;

  const int slot = tid & 7, rr = tid >> 3;
  const int ce = (slot ^ (rr & 7)) << 3;     // inverse-swizzled global col (x8 f16)

  f32x4 acc[8][4] = {};
  f16x8 av0[4][2], av1[4][2], bv0[2][2], bv1[2][2];
  const f16* alb = (const f16*)(smem + 131072);

  if (ALPHA) {
    // stage alphaT slice: (K/128) tiles x 256 rows fp16 -> annex at 128KiB
    const int ntl = K >> 7;
    const unsigned short* g0 = alp + (size_t)(zb * ntl) * Mtot + bm;
    uint4* s = (uint4*)(smem + 131072);
    const int nu4 = (ntl << 5);              // (ntl*256)/8
    for (int idx = tid; idx < nu4; idx += 512) {
      const int tt = idx >> 5;
      const int ru = (idx & 31) << 3;
      s[idx] = *(const uint4*)(g0 + (size_t)tt * Mtot + ru);
    }
  }

  auto stA = [&](int h, int Ts) {
    const int t_ = Ts >= NT ? Ts - NT : Ts;  // tail wrap: keep vmcnt ledger
    const unsigned kk = koff + (unsigned)(t_ << 6);
    char* l = smem + ((Ts & 1) << 16) + h * 16384 + wave * 1024;
#pragma unroll
    for (int p = 0; p < 2; ++p) {
      const unsigned off = (unsigned)(bm + p * 128 + h * 64 + rr) * (unsigned)lda + kk + ce;
      async_ld16(A + off, l + p * 8192);
    }
  };
  auto stB = [&](int h, int Ts) {
    const int t_ = Ts >= NT ? Ts - NT : Ts;
    const unsigned kk = koff + (unsigned)(t_ << 6);
    char* l = smem + ((Ts & 1) << 16) + 32768 + h * 16384 + wave * 1024;
#pragma unroll
    for (int p = 0; p < 2; ++p) {
      const unsigned off =
          (unsigned)(bn + p * 128 + (rr >> 5) * 64 + h * 32 + (rr & 31)) * (unsigned)ldb + kk + ce;
      async_ld16(B + off, l + p * 8192);
    }
  };
  auto rdA = [&](int bufc, int i, int ks) {
    const int r = wr * 64 + (i & 3) * 16 + mr;
    return *(const f16x8*)(smem + bufc + (i >> 2) * 16384 + r * 128 +
                           ((((ks << 2) | quad) ^ (mr & 7)) << 4));
  };
  auto rdB = [&](int bufc, int j, int ks) {
    const int r = wc * 32 + (j & 1) * 16 + mr;
    return *(const f16x8*)(smem + bufc + 32768 + (j >> 1) * 16384 + r * 128 +
                           ((((ks << 2) | quad) ^ (mr & 7)) << 4));
  };

  // prologue: stage H0..H6, wait for the 8 oldest (tile0's 4 halves)
  stA(0, 0); stB(0, 0); stA(1, 0); stB(1, 0);
  stA(0, 1); stB(0, 1); stA(1, 1);
  if (ALPHA) asm volatile("s_waitcnt lgkmcnt(0)" ::: "memory");  // alpha ds_writes
  asm volatile("s_waitcnt vmcnt(6)" ::: "memory");
  __builtin_amdgcn_s_barrier();

  for (int T = 0; T < NT; ++T) {
    const int bufc = (T & 1) << 16;
    f16 a0_[4], a1_[4];
    // ---- phase 0: read A-half0 (+alpha) | stage B1(T+1) | MFMA prev (4..7 x 2..3)
#pragma unroll
    for (int i = 0; i < 4; ++i) { av0[i][0] = rdA(bufc, i, 0); av0[i][1] = rdA(bufc, i, 1); }
    if (ALPHA) {
#pragma unroll
      for (int i = 0; i < 4; ++i) a0_[i] = alb[(T >> 1) * 256 + wr * 128 + i * 16 + mr];
    }
    stB(1, T + 1);
    __builtin_amdgcn_s_barrier();
    asm volatile("s_waitcnt lgkmcnt(0)" ::: "memory");
    __builtin_amdgcn_sched_barrier(0);
    if (ALPHA) {
#pragma unroll
      for (int i = 0; i < 4; ++i) { av0[i][0] = av0[i][0] * a0_[i]; av0[i][1] = av0[i][1] * a0_[i]; }
    }
    if (T) {
      __builtin_amdgcn_s_setprio(1);
#pragma unroll
      for (int i = 0; i < 4; ++i)
#pragma unroll
        for (int j = 0; j < 2; ++j) {
          MFMA16(acc[4 + i][2 + j], av1[i][0], bv1[j][0]);
          MFMA16(acc[4 + i][2 + j], av1[i][1], bv1[j][1]);
        }
      __builtin_amdgcn_s_setprio(0);
    }
    __builtin_amdgcn_s_barrier();
    // ---- phase 1: read B-half0 | stage A0(T+2) | MFMA (0..3 x 0..1)
#pragma unroll
    for (int j = 0; j < 2; ++j) { bv0[j][0] = rdB(bufc, j, 0); bv0[j][1] = rdB(bufc, j, 1); }
    stA(0, T + 2);
    __builtin_amdgcn_s_barrier();
    asm volatile("s_waitcnt lgkmcnt(0)" ::: "memory");
    __builtin_amdgcn_sched_barrier(0);
    __builtin_amdgcn_s_setprio(1);
#pragma unroll
    for (int i = 0; i < 4; ++i)
#pragma unroll
      for (int j = 0; j < 2; ++j) {
        MFMA16(acc[i][j], av0[i][0], bv0[j][0]);
        MFMA16(acc[i][j], av0[i][1], bv0[j][1]);
      }
    __builtin_amdgcn_s_setprio(0);
    __builtin_amdgcn_s_barrier();
    // ---- phase 2: read A-half1 (+alpha) | stage B0(T+2) | MFMA (4..7 x 0..1)
#pragma unroll
    for (int i = 0; i < 4; ++i) { av1[i][0] = rdA(bufc, 4 + i, 0); av1[i][1] = rdA(bufc, 4 + i, 1); }
    if (ALPHA) {
#pragma unroll
      for (int i = 0; i < 4; ++i) a1_[i] = alb[(T >> 1) * 256 + wr * 128 + 64 + i * 16 + mr];
    }
    stB(0, T + 2);
    __builtin_amdgcn_s_barrier();
    asm volatile("s_waitcnt lgkmcnt(0)" ::: "memory");
    __builtin_amdgcn_sched_barrier(0);
    if (ALPHA) {
#pragma unroll
      for (int i = 0; i < 4; ++i) { av1[i][0] = av1[i][0] * a1_[i]; av1[i][1] = av1[i][1] * a1_[i]; }
    }
    __builtin_amdgcn_s_setprio(1);
#pragma unroll
    for (int i = 0; i < 4; ++i)
#pragma unroll
      for (int j = 0; j < 2; ++j) {
        MFMA16(acc[4 + i][j], av1[i][0], bv0[j][0]);
        MFMA16(acc[4 + i][j], av1[i][1], bv0[j][1]);
      }
    __builtin_amdgcn_s_setprio(0);
    __builtin_amdgcn_s_barrier();
    // ---- phase 3: read B-half1 | stage A1(T+2) | MFMA (0..3 x 2..3) | vmcnt(6)
#pragma unroll
    for (int j = 0; j < 2; ++j) { bv1[j][0] = rdB(bufc, 2 + j, 0); bv1[j][1] = rdB(bufc, 2 + j, 1); }
    stA(1, T + 2);
    __builtin_amdgcn_s_barrier();
    asm volatile("s_waitcnt lgkmcnt(0)" ::: "memory");
    __builtin_amdgcn_sched_barrier(0);
    __builtin_amdgcn_s_setprio(1);
#pragma unroll
    for (int i = 0; i < 4; ++i)
#pragma unroll
      for (int j = 0; j < 2; ++j) {
        MFMA16(acc[i][2 + j], av0[i][0], bv1[j][0]);
        MFMA16(acc[i][2 + j], av0[i][1], bv1[j][1]);
      }
    __builtin_amdgcn_s_setprio(0);
    asm volatile("s_waitcnt vmcnt(6)" ::: "memory");
    __builtin_amdgcn_s_barrier();
  }
  // final cross-tile cluster: (4..7 x 2..3) of tile NT-1
  __builtin_amdgcn_s_setprio(1);
#pragma unroll
  for (int i = 0; i < 4; ++i)
#pragma unroll
    for (int j = 0; j < 2; ++j) {
      MFMA16(acc[4 + i][2 + j], av1[i][0], bv1[j][0]);
      MFMA16(acc[4 + i][2 + j], av1[i][1], bv1[j][1]);
    }
  __builtin_amdgcn_s_setprio(0);
  asm volatile("s_waitcnt vmcnt(0)" ::: "memory");
  __builtin_amdgcn_s_barrier();

  // ---- epilogue ---------------------------------------------------------
#pragma unroll
  for (int i = 0; i < 8; ++i) {
#pragma unroll
    for (int j = 0; j < 4; ++j) {
      const int col = bn + wc * 64 + j * 16 + mr;
      float bb = 0.f;
      if (HASBIAS) bb = bias[col];
#pragma unroll
      for (int r = 0; r < 4; ++r) {
        const int row = bm + wr * 128 + i * 16 + quad * 4 + r;
        float v = acc[i][j][r];
        if (HASBIAS) v += bb;
        if (RELU) v = fmaxf(v, 0.f);
        if (EPI == 2)
          atomicAdd(&((float*)Cp)[(size_t)row * ldc + col], v);
        else
          ((unsigned short*)Cp)[(size_t)row * ldc + col] = f2h(v);
      }
    }
  }
}

// ---------------------------------------------------------------------------
// qk256: S = Q·K^T with fused exp + per-(row,128-col-half) m/l stats.
// (verified R1 — unchanged)
// ---------------------------------------------------------------------------
__global__ __launch_bounds__(512, 2) void qk256(
    const unsigned short* __restrict__ A, const unsigned short* __restrict__ B,
    unsigned short* __restrict__ P, float* __restrict__ stm,
    float* __restrict__ stl, int M, int K, int lda, int ldb, int ldc) {
  extern __shared__ char smem[];
  const int NT = K >> 6;

  const int b = blockIdx.x;
  const int xcd = b & 7, c = b >> 3;
  const int mb = c & 31, nb = (xcd << 2) | (c >> 5);
  const int bm = mb << 8, bn = nb << 8;

  const int tid = threadIdx.x;
  const int wave = tid >> 6, lane = tid & 63;
  const int wr = wave >> 2, wc = wave & 3;
  const int mr = lane & 15, quad = lane >> 4;

  const int slot = tid & 7, rr = tid >> 3;
  const int ce = (slot ^ (rr & 7)) << 3;

  f32x4 acc[8][4] = {};
  f16x8 av0[4][2], av1[4][2], bv0[2][2], bv1[2][2];

  auto stA = [&](int h, int Ts) {
    const int t = Ts >= NT ? Ts - NT : Ts;
    const int kk = t << 6;
    char* l = smem + ((Ts & 1) << 16) + h * 16384 + wave * 1024;
#pragma unroll
    for (int p = 0; p < 2; ++p) {
      const unsigned off = (unsigned)(bm + p * 128 + h * 64 + rr) * (unsigned)lda + kk + ce;
      async_ld16(A + off, l + p * 8192);
    }
  };
  auto stB = [&](int h, int Ts) {
    const int t = Ts >= NT ? Ts - NT : Ts;
    const int kk = t << 6;
    char* l = smem + ((Ts & 1) << 16) + 32768 + h * 16384 + wave * 1024;
#pragma unroll
    for (int p = 0; p < 2; ++p) {
      const unsigned off =
          (unsigned)(bn + p * 128 + (rr >> 5) * 64 + h * 32 + (rr & 31)) * (unsigned)ldb + kk + ce;
      async_ld16(B + off, l + p * 8192);
    }
  };
  auto rdA = [&](int bufc, int i, int ks) {
    const int r = wr * 64 + (i & 3) * 16 + mr;
    return *(const f16x8*)(smem + bufc + (i >> 2) * 16384 + r * 128 +
                           ((((ks << 2) | quad) ^ (mr & 7)) << 4));
  };
  auto rdB = [&](int bufc, int j, int ks) {
    const int r = wc * 32 + (j & 1) * 16 + mr;
    return *(const f16x8*)(smem + bufc + 32768 + (j >> 1) * 16384 + r * 128 +
                           ((((ks << 2) | quad) ^ (mr & 7)) << 4));
  };

  stA(0, 0); stB(0, 0); stA(1, 0); stB(1, 0);
  stA(0, 1); stB(0, 1); stA(1, 1);
  asm volatile("s_waitcnt vmcnt(6)" ::: "memory");
  __builtin_amdgcn_s_barrier();

  for (int T = 0; T < NT; ++T) {
    const int bufc = (T & 1) << 16;
#pragma unroll
    for (int i = 0; i < 4; ++i) { av0[i][0] = rdA(bufc, i, 0); av0[i][1] = rdA(bufc, i, 1); }
    stB(1, T + 1);
    __builtin_amdgcn_s_barrier();
    asm volatile("s_waitcnt lgkmcnt(0)" ::: "memory");
    __builtin_amdgcn_sched_barrier(0);
    if (T) {
      __builtin_amdgcn_s_setprio(1);
#pragma unroll
      for (int i = 0; i < 4; ++i)
#pragma unroll
        for (int j = 0; j < 2; ++j) {
          MFMA16(acc[4 + i][2 + j], av1[i][0], bv1[j][0]);
          MFMA16(acc[4 + i][2 + j], av1[i][1], bv1[j][1]);
        }
      __builtin_amdgcn_s_setprio(0);
    }
    __builtin_amdgcn_s_barrier();
#pragma unroll
    for (int j = 0; j < 2; ++j) { bv0[j][0] = rdB(bufc, j, 0); bv0[j][1] = rdB(bufc, j, 1); }
    stA(0, T + 2);
    __builtin_amdgcn_s_barrier();
    asm volatile("s_waitcnt lgkmcnt(0)" ::: "memory");
    __builtin_amdgcn_sched_barrier(0);
    __builtin_amdgcn_s_setprio(1);
#pragma unroll
    for (int i = 0; i < 4; ++i)
#pragma unroll
      for (int j = 0; j < 2; ++j) {
        MFMA16(acc[i][j], av0[i][0], bv0[j][0]);
        MFMA16(acc[i][j], av0[i][1], bv0[j][1]);
      }
    __builtin_amdgcn_s_setprio(0);
    __builtin_amdgcn_s_barrier();
#pragma unroll
    for (int i = 0; i < 4; ++i) { av1[i][0] = rdA(bufc, 4 + i, 0); av1[i][1] = rdA(bufc, 4 + i, 1); }
    stB(0, T + 2);
    __builtin_amdgcn_s_barrier();
    asm volatile("s_waitcnt lgkmcnt(0)" ::: "memory");
    __builtin_amdgcn_sched_barrier(0);
    __builtin_amdgcn_s_setprio(1);
#pragma unroll
    for (int i = 0; i < 4; ++i)
#pragma unroll
      for (int j = 0; j < 2; ++j) {
        MFMA16(acc[4 + i][j], av1[i][0], bv0[j][0]);
        MFMA16(acc[4 + i][j], av1[i][1], bv0[j][1]);
      }
    __builtin_amdgcn_s_setprio(0);
    __builtin_amdgcn_s_barrier();
#pragma unroll
    for (int j = 0; j < 2; ++j) { bv1[j][0] = rdB(bufc, 2 + j, 0); bv1[j][1] = rdB(bufc, 2 + j, 1); }
    stA(1, T + 2);
    __builtin_amdgcn_s_barrier();
    asm volatile("s_waitcnt lgkmcnt(0)" ::: "memory");
    __builtin_amdgcn_sched_barrier(0);
    __builtin_amdgcn_s_setprio(1);
#pragma unroll
    for (int i = 0; i < 4; ++i)
#pragma unroll
      for (int j = 0; j < 2; ++j) {
        MFMA16(acc[i][2 + j], av0[i][0], bv1[j][0]);
        MFMA16(acc[i][2 + j], av0[i][1], bv1[j][1]);
      }
    __builtin_amdgcn_s_setprio(0);
    asm volatile("s_waitcnt vmcnt(6)" ::: "memory");
    __builtin_amdgcn_s_barrier();
  }
  __builtin_amdgcn_s_setprio(1);
#pragma unroll
  for (int i = 0; i < 4; ++i)
#pragma unroll
    for (int j = 0; j < 2; ++j) {
      MFMA16(acc[4 + i][2 + j], av1[i][0], bv1[j][0]);
      MFMA16(acc[4 + i][2 + j], av1[i][1], bv1[j][1]);
    }
  __builtin_amdgcn_s_setprio(0);
  asm volatile("s_waitcnt vmcnt(0)" ::: "memory");
  __builtin_amdgcn_s_barrier();

  float* sred = (float*)smem;
  float* ssum = (float*)(smem + 4096);
  const int hc = wc >> 1;
  float Mh[8][4];

#pragma unroll
  for (int i = 0; i < 8; ++i)
#pragma unroll
    for (int r = 0; r < 4; ++r) {
      float m = acc[i][0][r];
#pragma unroll
      for (int j = 1; j < 4; ++j) m = fmaxf(m, acc[i][j][r]);
      m = fmaxf(m, __shfl_xor(m, 1));
      m = fmaxf(m, __shfl_xor(m, 2));
      m = fmaxf(m, __shfl_xor(m, 4));
      m = fmaxf(m, __shfl_xor(m, 8));
      if (mr == 0) sred[(wr * 128 + i * 16 + quad * 4 + r) * 4 + wc] = m;
    }
  __syncthreads();
#pragma unroll
  for (int i = 0; i < 8; ++i)
#pragma unroll
    for (int r = 0; r < 4; ++r) {
      const int row_l = wr * 128 + i * 16 + quad * 4 + r;
      Mh[i][r] = fmaxf(sred[row_l * 4 + 2 * hc], sred[row_l * 4 + 2 * hc + 1]);
    }
#pragma unroll
  for (int i = 0; i < 8; ++i)
#pragma unroll
    for (int r = 0; r < 4; ++r) {
      const int row_l = wr * 128 + i * 16 + quad * 4 + r;
      float l = 0.f;
#pragma unroll
      for (int j = 0; j < 4; ++j) {
        const float e = __expf(acc[i][j][r] - Mh[i][r]);
        P[(size_t)(bm + row_l) * ldc + (bn + wc * 64 + j * 16 + mr)] = f2h(e);
        l += e;
      }
      l += __shfl_xor(l, 1);
      l += __shfl_xor(l, 2);
      l += __shfl_xor(l, 4);
      l += __shfl_xor(l, 8);
      if (mr == 0) ssum[row_l * 4 + wc] = l;
    }
  __syncthreads();
  if ((wc & 1) == 0 && mr == 0) {
#pragma unroll
    for (int i = 0; i < 8; ++i)
#pragma unroll
      for (int r = 0; r < 4; ++r) {
        const int row_l = wr * 128 + i * 16 + quad * 4 + r;
        const int tile = nb * 2 + hc;
        stm[(size_t)tile * M + bm + row_l] = Mh[i][r];
        stl[(size_t)tile * M + bm + row_l] =
            ssum[row_l * 4 + 2 * hc] + ssum[row_l * 4 + 2 * hc + 1];
      }
  }
}

// per-row combine: M = max_t m_t, L = sum_t l_t*exp(m_t-M)
__global__ __launch_bounds__(256) void combine_alpha(
    const float* __restrict__ stm, const float* __restrict__ stl,
    unsigned short* __restrict__ alp, int ntile, int Mtot) {
  const int row = blockIdx.x * 4 + (threadIdx.x >> 6);
  const int t = threadIdx.x & 63;
  float m = (t < ntile) ? stm[(size_t)t * Mtot + row] : -1e30f;
  float M = m;
#pragma unroll
  for (int o = 1; o < 64; o <<= 1) M = fmaxf(M, __shfl_xor(M, o));
  float l = (t < ntile) ? stl[(size_t)t * Mtot + row] : 0.f;
  float c = l * __expf(m - M);
#pragma unroll
  for (int o = 1; o < 64; o <<= 1) c += __shfl_xor(c, o);
  if (t < ntile) alp[(size_t)t * Mtot + row] = f2h(__expf(m - M) / c);
}

__global__ __launch_bounds__(256) void cvt_f16(const float* __restrict__ in,
                                               unsigned short* __restrict__ out, int n) {
  int i = blockIdx.x * 256 + threadIdx.x;
  if (i < n) out[i] = f2h(in[i]);
}

__global__ __launch_bounds__(256) void bias_fill(float* __restrict__ out,
                                                 const float* __restrict__ b, int d) {
  int i = blockIdx.x * 256 + threadIdx.x;
  out[i] = b[i % d];
}

// V [8192 x 768] fp32 -> vT [768 x 8192] fp16
__global__ __launch_bounds__(256) void vt_kernel(const float* __restrict__ V,
                                                 unsigned short* __restrict__ vT) {
  __shared__ float t[32][33];
  const int bx = blockIdx.x, by = blockIdx.y;
  const int x = threadIdx.x, y = threadIdx.y;
#pragma unroll
  for (int r = 0; r < 4; ++r)
    t[y + r * 8][x] = V[(size_t)(by * 32 + y + r * 8) * 768 + bx * 32 + x];
  __syncthreads();
#pragma unroll
  for (int r = 0; r < 4; ++r)
    vT[(size_t)(bx * 32 + y + r * 8) * 8192 + by * 32 + x] = f2h(t[x][y + r * 8]);
}

// ---------------------------------------------------------------------------
extern "C" void kernel_launch(void* const* d_in, const int* in_sizes, int n_in,
                              void* d_out, int out_size, void* d_ws, size_t ws_size,
                              hipStream_t stream) {
  const int N = 8192, D = 768, DFF = 2048;
  const float* Q  = (const float*)d_in[0];
  const float* Km = (const float*)d_in[1];
  const float* V  = (const float*)d_in[2];
  const float* W1 = (const float*)d_in[3];
  const float* b1 = (const float*)d_in[4];
  const float* W2 = (const float*)d_in[5];
  const float* b2 = (const float*)d_in[6];

  char* w = (char*)d_ws;
  size_t off = 0;
  auto take = [&](size_t bytes) { void* p = w + off; off += bytes; return p; };
  unsigned short* qh   = (unsigned short*)take((size_t)N * D * 2);
  unsigned short* kh   = (unsigned short*)take((size_t)N * D * 2);
  unsigned short* vT   = (unsigned short*)take((size_t)N * D * 2);
  unsigned short* ctx16= (unsigned short*)take((size_t)N * D * 2);
  float*          ctx32= (float*)take((size_t)N * D * 4);
  unsigned short* hb   = (unsigned short*)take((size_t)N * DFF * 2);
  unsigned short* w1h  = (unsigned short*)take((size_t)DFF * D * 2);
  unsigned short* w2h  = (unsigned short*)take((size_t)D * DFF * 2);
  float*          stm  = (float*)take((size_t)64 * N * 4);
  float*          stl  = (float*)take((size_t)64 * N * 4);
  unsigned short* alp  = (unsigned short*)take((size_t)64 * N * 2);  // [tile][row]
  unsigned short* Pp   = (unsigned short*)take((size_t)N * N * 2);   // P' fp16, 128 MB
  (void)ws_size;

  cvt_f16<<<(N * D) / 256, 256, 0, stream>>>(Q, qh, N * D);
  cvt_f16<<<(N * D) / 256, 256, 0, stream>>>(Km, kh, N * D);
  vt_kernel<<<dim3(D / 32, N / 32), dim3(32, 8), 0, stream>>>(V, vT);
  cvt_f16<<<(DFF * D) / 256, 256, 0, stream>>>(W1, w1h, DFF * D);
  cvt_f16<<<(D * DFF) / 256, 256, 0, stream>>>(W2, w2h, D * DFF);
  hipMemsetAsync(ctx32, 0, (size_t)N * D * 4, stream);
  bias_fill<<<(N * D) / 256, 256, 0, stream>>>((float*)d_out, b2, D);

  {  // QK^T 256^2 8-phase with fused exp + per-(row,128-tile) stats
    hipFuncSetAttribute((const void*)qk256,
                        hipFuncAttributeMaxDynamicSharedMemorySize, 131072);
    qk256<<<(N / 256) * (N / 256), 512, 131072, stream>>>(
        qh, kh, Pp, stm, stl, N, D, D, D, N);
  }
  combine_alpha<<<N / 4, 256, 0, stream>>>(stm, stl, alp, 64, N);

  {  // ctx32 += (alphaT .* P') . V — 256^2 8-phase, sl=2, XCD-placed, atomics
    const int nt = D / 256, mt = N / 256, sl = 2;   // grid 192 = 1 round
    const int smem_sz = 131072 + ((N / sl) >> 7) * 256 * 2;  // +16KB alpha annex
    hipFuncSetAttribute((const void*)gemm256<2, false, false, true, true>,
                        hipFuncAttributeMaxDynamicSharedMemorySize, smem_sz);
    gemm256<2, false, false, true, true><<<nt * mt * sl, 512, smem_sz, stream>>>(
        Pp, vT, ctx32, nullptr, alp, N,
        N / sl, N, N, D, nt, mt, sl);
  }
  cvt_f16<<<(N * D) / 256, 256, 0, stream>>>(ctx32, ctx16, N * D);

  {  // h = relu(ctx . W1^T + b1)  fp16 — grid 256, XCD-placed
    const int nt = DFF / 256, mt = N / 256;
    hipFuncSetAttribute((const void*)gemm256<0, true, true, false, true>,
                        hipFuncAttributeMaxDynamicSharedMemorySize, 131072);
    gemm256<0, true, true, false, true><<<nt * mt, 512, 131072, stream>>>(
        ctx16, w1h, hb, b1, nullptr, N,
        D, D, D, DFF, nt, mt, 1);
  }
  {  // out += h . W2^T  (bias pre-filled) — sl=2, grid 192, XCD-placed
    const int nt = D / 256, mt = N / 256, sl = 2;
    hipFuncSetAttribute((const void*)gemm256<2, false, false, false, true>,
                        hipFuncAttributeMaxDynamicSharedMemorySize, 131072);
    gemm256<2, false, false, false, true><<<nt * mt * sl, 512, 131072, stream>>>(
        hb, w2h, (float*)d_out, nullptr, nullptr, N,
        DFF / sl, DFF, DFF, D, nt, mt, sl);
  }
}

// Round 5
// 553.255 us; speedup vs baseline: 1.1884x; 1.0412x over previous
//
#include <hip/hip_runtime.h>
#include <cstdint>
#include <cstddef>

#define DEV __device__ __forceinline__

typedef _Float16 f16;
typedef __attribute__((ext_vector_type(8))) _Float16 f16x8;
typedef __attribute__((ext_vector_type(4))) float f32x4;

DEV unsigned short f2h(float f) {
  f16 h = (f16)f;
  return __builtin_bit_cast(unsigned short, h);
}

DEV void async_ld16(const void* g, void* l) {
  __builtin_amdgcn_global_load_lds(
      (__attribute__((address_space(1))) unsigned int*)(uintptr_t)g,
      (__attribute__((address_space(3))) unsigned int*)(uint32_t)(uintptr_t)l,
      16, 0, 0);
}

#define MFMA16(d, a, b_) (d) = __builtin_amdgcn_mfma_f32_16x16x32_f16((a), (b_), (d), 0, 0, 0)

// ---------------------------------------------------------------------------
// gemm256: C[M x N] = A[M x K] * B[N x K]^T  (K-contiguous, f16-as-ushort)
// 256xBN tile (BN in {256,192}), BK=64, 8 waves (2Mx4N), 8-phase pipeline
// (schedule verified R1-R3; BN=192 changes ONLY the B row<->LDS mapping and
// the hi-cluster width — phase/barrier/vmcnt structure identical).
//   per-tile loads/thread: BN=256 -> 8 (A 2+2, B 2+2); BN=192 -> 7 (B1 = 1).
//   Both: end-of-tile outstanding = A0+B0+A1 of T+2 = 6 -> vmcnt(6) unchanged.
// B region mapping (within-region row rb -> global B row g):
//   BN=256: g = (rb/32)*64 + h*32 + rb%32      (each half = 2 x 8KB units)
//   BN=192 h=0: g = (u*2 + rr/32)*48 + rr%32   (2 units; feeds bv j=0,1)
//   BN=192 h=1: g = (rr/16)*48 + 32 + rr%16    (1 unit;  feeds bv j=2)
//   (checked: wc=1,j=1,mr -> rb=48+mr -> g=64+mr = need 1*48+16+mr ✓;
//    wc=3,h=1,mr -> rb=wc*16+mr -> g=176+mr = need 3*48+32+mr ✓)
// EPI: 0 = fp16 store (+bias/relu), 2 = fp32 atomicAdd.
// ALPHA: alphaT[(K/128) x 256] slice staged to LDS annex at 2*BUFSZ,
// scales av0 at phase0 / av1 at phase2.
// XCD: per-XCD nb-inner placement (A-panel sharers co-resident on one XCD);
// requires mt%8==0, grid == nt*mt*sl.
// ---------------------------------------------------------------------------
template <int BN, int EPI, bool RELU, bool HASBIAS, bool ALPHA, bool XCD>
__global__ __launch_bounds__(512, 2) void gemm256(
    const unsigned short* __restrict__ A, const unsigned short* __restrict__ B,
    void* __restrict__ Cp, const float* __restrict__ bias,
    const unsigned short* __restrict__ alp, int Mtot,
    int K, int lda, int ldb, int ldc, int nt, int mt, int sl) {
  extern __shared__ char smem[];
  constexpr int FN = BN / 64;              // 4 or 3
  constexpr int WCW = BN / 4;              // per-wave col width: 64 or 48
  constexpr int BUFSZ = 32768 + BN * 128;  // A 32KB + B (32 or 24 KB)
  const int NT = K >> 6;

  int mb, nb, zb;
  {
    const int b = blockIdx.x;
    if (XCD) {
      const int xcd = b & 7, q = b >> 3;
      nb = q % nt;
      const int rest = q / nt;
      zb = rest % sl;
      mb = xcd * (mt >> 3) + rest / sl;
    } else {
      nb = b % nt;
      const int t = b / nt;
      mb = t % mt;
      zb = t / mt;
    }
  }
  const int bm = mb << 8, bn = nb * BN;
  const unsigned koff = (unsigned)zb * (unsigned)K;

  const int tid = threadIdx.x;
  const int wave = tid >> 6, lane = tid & 63;
  const int wr = wave >> 2, wc = wave & 3;   // wave grid 2 x 4
  const int mr = lane & 15, quad = lane >> 4;

  const int slot = tid & 7, rr = tid >> 3;
  const int ce = (slot ^ (rr & 7)) << 3;     // inverse-swizzled global col (x8 f16)

  f32x4 acc[8][FN] = {};
  f16x8 av0[4][2], av1[4][2], bv0[2][2], bv1[FN - 2][2];
  const f16* alb = (const f16*)(smem + 2 * BUFSZ);

  if (ALPHA) {
    const int ntl = K >> 7;
    const unsigned short* g0 = alp + (size_t)(zb * ntl) * Mtot + bm;
    uint4* s = (uint4*)(smem + 2 * BUFSZ);
    const int nu4 = (ntl << 5);
    for (int idx = tid; idx < nu4; idx += 512) {
      const int tt = idx >> 5;
      const int ru = (idx & 31) << 3;
      s[idx] = *(const uint4*)(g0 + (size_t)tt * Mtot + ru);
    }
  }

  auto stA = [&](int h, int Ts) {
    const int t_ = Ts >= NT ? Ts - NT : Ts;  // tail wrap: keep vmcnt ledger
    const unsigned kk = koff + (unsigned)(t_ << 6);
    char* l = smem + (Ts & 1) * BUFSZ + h * 16384 + wave * 1024;
#pragma unroll
    for (int p = 0; p < 2; ++p) {
      const unsigned off = (unsigned)(bm + p * 128 + h * 64 + rr) * (unsigned)lda + kk + ce;
      async_ld16(A + off, l + p * 8192);
    }
  };
  auto stB = [&](int h, int Ts) {
    const int t_ = Ts >= NT ? Ts - NT : Ts;
    const unsigned kk = koff + (unsigned)(t_ << 6);
    char* l = smem + (Ts & 1) * BUFSZ + 32768 + h * 16384 + wave * 1024;
    if (BN == 256) {
#pragma unroll
      for (int p = 0; p < 2; ++p) {
        const int g = bn + p * 128 + (rr >> 5) * 64 + h * 32 + (rr & 31);
        async_ld16(B + ((unsigned)g * (unsigned)ldb + kk + ce), l + p * 8192);
      }
    } else if (h == 0) {
#pragma unroll
      for (int p = 0; p < 2; ++p) {
        const int g = bn + (p * 2 + (rr >> 5)) * 48 + (rr & 31);
        async_ld16(B + ((unsigned)g * (unsigned)ldb + kk + ce), l + p * 8192);
      }
    } else {
      const int g = bn + (rr >> 4) * 48 + 32 + (rr & 15);
      async_ld16(B + ((unsigned)g * (unsigned)ldb + kk + ce), l);
    }
  };
  auto rdA = [&](int bufc, int i, int ks) {
    const int r = wr * 64 + (i & 3) * 16 + mr;   // r&7 == mr&7
    return *(const f16x8*)(smem + bufc + (i >> 2) * 16384 + r * 128 +
                           ((((ks << 2) | quad) ^ (mr & 7)) << 4));
  };
  auto rdB0 = [&](int bufc, int j, int ks) {   // half0: j = 0,1
    const int rb = wc * 32 + j * 16 + mr;      // rb&7 == mr&7
    return *(const f16x8*)(smem + bufc + 32768 + rb * 128 +
                           ((((ks << 2) | quad) ^ (mr & 7)) << 4));
  };
  auto rdB1 = [&](int bufc, int j, int ks) {   // half1: j = 2..FN-1
    const int rb = (BN == 256) ? (wc * 32 + (j - 2) * 16 + mr) : (wc * 16 + mr);
    return *(const f16x8*)(smem + bufc + 32768 + 16384 + rb * 128 +
                           ((((ks << 2) | quad) ^ (mr & 7)) << 4));
  };

  // prologue: stage tile0 (A0,B0,A1,B1) + tile1 (A0,B0,A1); wait tile0 landed
  stA(0, 0); stB(0, 0); stA(1, 0); stB(1, 0);
  stA(0, 1); stB(0, 1); stA(1, 1);
  if (ALPHA) asm volatile("s_waitcnt lgkmcnt(0)" ::: "memory");
  asm volatile("s_waitcnt vmcnt(6)" ::: "memory");
  __builtin_amdgcn_s_barrier();

  for (int T = 0; T < NT; ++T) {
    const int bufc = (T & 1) * BUFSZ;
    f16 a0_[4], a1_[4];
    // ---- phase 0: read A-half0 (+alpha) | stage B1(T+1) | MFMA prev (4..7 x hi)
#pragma unroll
    for (int i = 0; i < 4; ++i) { av0[i][0] = rdA(bufc, i, 0); av0[i][1] = rdA(bufc, i, 1); }
    if (ALPHA) {
#pragma unroll
      for (int i = 0; i < 4; ++i) a0_[i] = alb[(T >> 1) * 256 + wr * 128 + i * 16 + mr];
    }
    stB(1, T + 1);
    __builtin_amdgcn_s_barrier();
    asm volatile("s_waitcnt lgkmcnt(0)" ::: "memory");
    __builtin_amdgcn_sched_barrier(0);
    if (ALPHA) {
#pragma unroll
      for (int i = 0; i < 4; ++i) { av0[i][0] = av0[i][0] * a0_[i]; av0[i][1] = av0[i][1] * a0_[i]; }
    }
    if (T) {
      __builtin_amdgcn_s_setprio(1);
#pragma unroll
      for (int i = 0; i < 4; ++i)
#pragma unroll
        for (int j = 0; j < FN - 2; ++j) {
          MFMA16(acc[4 + i][2 + j], av1[i][0], bv1[j][0]);
          MFMA16(acc[4 + i][2 + j], av1[i][1], bv1[j][1]);
        }
      __builtin_amdgcn_s_setprio(0);
    }
    __builtin_amdgcn_s_barrier();
    // ---- phase 1: read B-half0 | stage A0(T+2) | MFMA (0..3 x 0..1)
#pragma unroll
    for (int j = 0; j < 2; ++j) { bv0[j][0] = rdB0(bufc, j, 0); bv0[j][1] = rdB0(bufc, j, 1); }
    stA(0, T + 2);
    __builtin_amdgcn_s_barrier();
    asm volatile("s_waitcnt lgkmcnt(0)" ::: "memory");
    __builtin_amdgcn_sched_barrier(0);
    __builtin_amdgcn_s_setprio(1);
#pragma unroll
    for (int i = 0; i < 4; ++i)
#pragma unroll
      for (int j = 0; j < 2; ++j) {
        MFMA16(acc[i][j], av0[i][0], bv0[j][0]);
        MFMA16(acc[i][j], av0[i][1], bv0[j][1]);
      }
    __builtin_amdgcn_s_setprio(0);
    __builtin_amdgcn_s_barrier();
    // ---- phase 2: read A-half1 (+alpha) | stage B0(T+2) | MFMA (4..7 x 0..1)
#pragma unroll
    for (int i = 0; i < 4; ++i) { av1[i][0] = rdA(bufc, 4 + i, 0); av1[i][1] = rdA(bufc, 4 + i, 1); }
    if (ALPHA) {
#pragma unroll
      for (int i = 0; i < 4; ++i) a1_[i] = alb[(T >> 1) * 256 + wr * 128 + 64 + i * 16 + mr];
    }
    stB(0, T + 2);
    __builtin_amdgcn_s_barrier();
    asm volatile("s_waitcnt lgkmcnt(0)" ::: "memory");
    __builtin_amdgcn_sched_barrier(0);
    if (ALPHA) {
#pragma unroll
      for (int i = 0; i < 4; ++i) { av1[i][0] = av1[i][0] * a1_[i]; av1[i][1] = av1[i][1] * a1_[i]; }
    }
    __builtin_amdgcn_s_setprio(1);
#pragma unroll
    for (int i = 0; i < 4; ++i)
#pragma unroll
      for (int j = 0; j < 2; ++j) {
        MFMA16(acc[4 + i][j], av1[i][0], bv0[j][0]);
        MFMA16(acc[4 + i][j], av1[i][1], bv0[j][1]);
      }
    __builtin_amdgcn_s_setprio(0);
    __builtin_amdgcn_s_barrier();
    // ---- phase 3: read B-half1 | stage A1(T+2) | MFMA (0..3 x hi) | vmcnt(6)
#pragma unroll
    for (int j = 0; j < FN - 2; ++j) { bv1[j][0] = rdB1(bufc, 2 + j, 0); bv1[j][1] = rdB1(bufc, 2 + j, 1); }
    stA(1, T + 2);
    __builtin_amdgcn_s_barrier();
    asm volatile("s_waitcnt lgkmcnt(0)" ::: "memory");
    __builtin_amdgcn_sched_barrier(0);
    __builtin_amdgcn_s_setprio(1);
#pragma unroll
    for (int i = 0; i < 4; ++i)
#pragma unroll
      for (int j = 0; j < FN - 2; ++j) {
        MFMA16(acc[i][2 + j], av0[i][0], bv1[j][0]);
        MFMA16(acc[i][2 + j], av0[i][1], bv1[j][1]);
      }
    __builtin_amdgcn_s_setprio(0);
    asm volatile("s_waitcnt vmcnt(6)" ::: "memory");
    __builtin_amdgcn_s_barrier();
  }
  // final cross-tile cluster: (4..7 x hi) of tile NT-1
  __builtin_amdgcn_s_setprio(1);
#pragma unroll
  for (int i = 0; i < 4; ++i)
#pragma unroll
    for (int j = 0; j < FN - 2; ++j) {
      MFMA16(acc[4 + i][2 + j], av1[i][0], bv1[j][0]);
      MFMA16(acc[4 + i][2 + j], av1[i][1], bv1[j][1]);
    }
  __builtin_amdgcn_s_setprio(0);
  asm volatile("s_waitcnt vmcnt(0)" ::: "memory");
  __builtin_amdgcn_s_barrier();

  // ---- epilogue ---------------------------------------------------------
#pragma unroll
  for (int i = 0; i < 8; ++i) {
#pragma unroll
    for (int j = 0; j < FN; ++j) {
      const int col = bn + wc * WCW + j * 16 + mr;
      float bb = 0.f;
      if (HASBIAS) bb = bias[col];
#pragma unroll
      for (int r = 0; r < 4; ++r) {
        const int row = bm + wr * 128 + i * 16 + quad * 4 + r;
        float v = acc[i][j][r];
        if (HASBIAS) v += bb;
        if (RELU) v = fmaxf(v, 0.f);
        if (EPI == 2)
          atomicAdd(&((float*)Cp)[(size_t)row * ldc + col], v);
        else
          ((unsigned short*)Cp)[(size_t)row * ldc + col] = f2h(v);
      }
    }
  }
}

// ---------------------------------------------------------------------------
// qk256: S = Q·K^T with fused exp + per-(row,128-col-half) m/l stats.
// (verified R1 — unchanged)
// ---------------------------------------------------------------------------
__global__ __launch_bounds__(512, 2) void qk256(
    const unsigned short* __restrict__ A, const unsigned short* __restrict__ B,
    unsigned short* __restrict__ P, float* __restrict__ stm,
    float* __restrict__ stl, int M, int K, int lda, int ldb, int ldc) {
  extern __shared__ char smem[];
  const int NT = K >> 6;

  const int b = blockIdx.x;
  const int xcd = b & 7, c = b >> 3;
  const int mb = c & 31, nb = (xcd << 2) | (c >> 5);
  const int bm = mb << 8, bn = nb << 8;

  const int tid = threadIdx.x;
  const int wave = tid >> 6, lane = tid & 63;
  const int wr = wave >> 2, wc = wave & 3;
  const int mr = lane & 15, quad = lane >> 4;

  const int slot = tid & 7, rr = tid >> 3;
  const int ce = (slot ^ (rr & 7)) << 3;

  f32x4 acc[8][4] = {};
  f16x8 av0[4][2], av1[4][2], bv0[2][2], bv1[2][2];

  auto stA = [&](int h, int Ts) {
    const int t = Ts >= NT ? Ts - NT : Ts;
    const int kk = t << 6;
    char* l = smem + ((Ts & 1) << 16) + h * 16384 + wave * 1024;
#pragma unroll
    for (int p = 0; p < 2; ++p) {
      const unsigned off = (unsigned)(bm + p * 128 + h * 64 + rr) * (unsigned)lda + kk + ce;
      async_ld16(A + off, l + p * 8192);
    }
  };
  auto stB = [&](int h, int Ts) {
    const int t = Ts >= NT ? Ts - NT : Ts;
    const int kk = t << 6;
    char* l = smem + ((Ts & 1) << 16) + 32768 + h * 16384 + wave * 1024;
#pragma unroll
    for (int p = 0; p < 2; ++p) {
      const unsigned off =
          (unsigned)(bn + p * 128 + (rr >> 5) * 64 + h * 32 + (rr & 31)) * (unsigned)ldb + kk + ce;
      async_ld16(B + off, l + p * 8192);
    }
  };
  auto rdA = [&](int bufc, int i, int ks) {
    const int r = wr * 64 + (i & 3) * 16 + mr;
    return *(const f16x8*)(smem + bufc + (i >> 2) * 16384 + r * 128 +
                           ((((ks << 2) | quad) ^ (mr & 7)) << 4));
  };
  auto rdB = [&](int bufc, int j, int ks) {
    const int r = wc * 32 + (j & 1) * 16 + mr;
    return *(const f16x8*)(smem + bufc + 32768 + (j >> 1) * 16384 + r * 128 +
                           ((((ks << 2) | quad) ^ (mr & 7)) << 4));
  };

  stA(0, 0); stB(0, 0); stA(1, 0); stB(1, 0);
  stA(0, 1); stB(0, 1); stA(1, 1);
  asm volatile("s_waitcnt vmcnt(6)" ::: "memory");
  __builtin_amdgcn_s_barrier();

  for (int T = 0; T < NT; ++T) {
    const int bufc = (T & 1) << 16;
#pragma unroll
    for (int i = 0; i < 4; ++i) { av0[i][0] = rdA(bufc, i, 0); av0[i][1] = rdA(bufc, i, 1); }
    stB(1, T + 1);
    __builtin_amdgcn_s_barrier();
    asm volatile("s_waitcnt lgkmcnt(0)" ::: "memory");
    __builtin_amdgcn_sched_barrier(0);
    if (T) {
      __builtin_amdgcn_s_setprio(1);
#pragma unroll
      for (int i = 0; i < 4; ++i)
#pragma unroll
        for (int j = 0; j < 2; ++j) {
          MFMA16(acc[4 + i][2 + j], av1[i][0], bv1[j][0]);
          MFMA16(acc[4 + i][2 + j], av1[i][1], bv1[j][1]);
        }
      __builtin_amdgcn_s_setprio(0);
    }
    __builtin_amdgcn_s_barrier();
#pragma unroll
    for (int j = 0; j < 2; ++j) { bv0[j][0] = rdB(bufc, j, 0); bv0[j][1] = rdB(bufc, j, 1); }
    stA(0, T + 2);
    __builtin_amdgcn_s_barrier();
    asm volatile("s_waitcnt lgkmcnt(0)" ::: "memory");
    __builtin_amdgcn_sched_barrier(0);
    __builtin_amdgcn_s_setprio(1);
#pragma unroll
    for (int i = 0; i < 4; ++i)
#pragma unroll
      for (int j = 0; j < 2; ++j) {
        MFMA16(acc[i][j], av0[i][0], bv0[j][0]);
        MFMA16(acc[i][j], av0[i][1], bv0[j][1]);
      }
    __builtin_amdgcn_s_setprio(0);
    __builtin_amdgcn_s_barrier();
#pragma unroll
    for (int i = 0; i < 4; ++i) { av1[i][0] = rdA(bufc, 4 + i, 0); av1[i][1] = rdA(bufc, 4 + i, 1); }
    stB(0, T + 2);
    __builtin_amdgcn_s_barrier();
    asm volatile("s_waitcnt lgkmcnt(0)" ::: "memory");
    __builtin_amdgcn_sched_barrier(0);
    __builtin_amdgcn_s_setprio(1);
#pragma unroll
    for (int i = 0; i < 4; ++i)
#pragma unroll
      for (int j = 0; j < 2; ++j) {
        MFMA16(acc[4 + i][j], av1[i][0], bv0[j][0]);
        MFMA16(acc[4 + i][j], av1[i][1], bv0[j][1]);
      }
    __builtin_amdgcn_s_setprio(0);
    __builtin_amdgcn_s_barrier();
#pragma unroll
    for (int j = 0; j < 2; ++j) { bv1[j][0] = rdB(bufc, 2 + j, 0); bv1[j][1] = rdB(bufc, 2 + j, 1); }
    stA(1, T + 2);
    __builtin_amdgcn_s_barrier();
    asm volatile("s_waitcnt lgkmcnt(0)" ::: "memory");
    __builtin_amdgcn_sched_barrier(0);
    __builtin_amdgcn_s_setprio(1);
#pragma unroll
    for (int i = 0; i < 4; ++i)
#pragma unroll
      for (int j = 0; j < 2; ++j) {
        MFMA16(acc[i][2 + j], av0[i][0], bv1[j][0]);
        MFMA16(acc[i][2 + j], av0[i][1], bv1[j][1]);
      }
    __builtin_amdgcn_s_setprio(0);
    asm volatile("s_waitcnt vmcnt(6)" ::: "memory");
    __builtin_amdgcn_s_barrier();
  }
  __builtin_amdgcn_s_setprio(1);
#pragma unroll
  for (int i = 0; i < 4; ++i)
#pragma unroll
    for (int j = 0; j < 2; ++j) {
      MFMA16(acc[4 + i][2 + j], av1[i][0], bv1[j][0]);
      MFMA16(acc[4 + i][2 + j], av1[i][1], bv1[j][1]);
    }
  __builtin_amdgcn_s_setprio(0);
  asm volatile("s_waitcnt vmcnt(0)" ::: "memory");
  __builtin_amdgcn_s_barrier();

  float* sred = (float*)smem;
  float* ssum = (float*)(smem + 4096);
  const int hc = wc >> 1;
  float Mh[8][4];

#pragma unroll
  for (int i = 0; i < 8; ++i)
#pragma unroll
    for (int r = 0; r < 4; ++r) {
      float m = acc[i][0][r];
#pragma unroll
      for (int j = 1; j < 4; ++j) m = fmaxf(m, acc[i][j][r]);
      m = fmaxf(m, __shfl_xor(m, 1));
      m = fmaxf(m, __shfl_xor(m, 2));
      m = fmaxf(m, __shfl_xor(m, 4));
      m = fmaxf(m, __shfl_xor(m, 8));
      if (mr == 0) sred[(wr * 128 + i * 16 + quad * 4 + r) * 4 + wc] = m;
    }
  __syncthreads();
#pragma unroll
  for (int i = 0; i < 8; ++i)
#pragma unroll
    for (int r = 0; r < 4; ++r) {
      const int row_l = wr * 128 + i * 16 + quad * 4 + r;
      Mh[i][r] = fmaxf(sred[row_l * 4 + 2 * hc], sred[row_l * 4 + 2 * hc + 1]);
    }
#pragma unroll
  for (int i = 0; i < 8; ++i)
#pragma unroll
    for (int r = 0; r < 4; ++r) {
      const int row_l = wr * 128 + i * 16 + quad * 4 + r;
      float l = 0.f;
#pragma unroll
      for (int j = 0; j < 4; ++j) {
        const float e = __expf(acc[i][j][r] - Mh[i][r]);
        P[(size_t)(bm + row_l) * ldc + (bn + wc * 64 + j * 16 + mr)] = f2h(e);
        l += e;
      }
      l += __shfl_xor(l, 1);
      l += __shfl_xor(l, 2);
      l += __shfl_xor(l, 4);
      l += __shfl_xor(l, 8);
      if (mr == 0) ssum[row_l * 4 + wc] = l;
    }
  __syncthreads();
  if ((wc & 1) == 0 && mr == 0) {
#pragma unroll
    for (int i = 0; i < 8; ++i)
#pragma unroll
      for (int r = 0; r < 4; ++r) {
        const int row_l = wr * 128 + i * 16 + quad * 4 + r;
        const int tile = nb * 2 + hc;
        stm[(size_t)tile * M + bm + row_l] = Mh[i][r];
        stl[(size_t)tile * M + bm + row_l] =
            ssum[row_l * 4 + 2 * hc] + ssum[row_l * 4 + 2 * hc + 1];
      }
  }
}

// per-row combine: M = max_t m_t, L = sum_t l_t*exp(m_t-M)
__global__ __launch_bounds__(256) void combine_alpha(
    const float* __restrict__ stm, const float* __restrict__ stl,
    unsigned short* __restrict__ alp, int ntile, int Mtot) {
  const int row = blockIdx.x * 4 + (threadIdx.x >> 6);
  const int t = threadIdx.x & 63;
  float m = (t < ntile) ? stm[(size_t)t * Mtot + row] : -1e30f;
  float M = m;
#pragma unroll
  for (int o = 1; o < 64; o <<= 1) M = fmaxf(M, __shfl_xor(M, o));
  float l = (t < ntile) ? stl[(size_t)t * Mtot + row] : 0.f;
  float c = l * __expf(m - M);
#pragma unroll
  for (int o = 1; o < 64; o <<= 1) c += __shfl_xor(c, o);
  if (t < ntile) alp[(size_t)t * Mtot + row] = f2h(__expf(m - M) / c);
}

__global__ __launch_bounds__(256) void cvt_f16(const float* __restrict__ in,
                                               unsigned short* __restrict__ out, int n) {
  int i = blockIdx.x * 256 + threadIdx.x;
  if (i < n) out[i] = f2h(in[i]);
}

__global__ __launch_bounds__(256) void bias_fill(float* __restrict__ out,
                                                 const float* __restrict__ b, int d) {
  int i = blockIdx.x * 256 + threadIdx.x;
  out[i] = b[i % d];
}

// V [8192 x 768] fp32 -> vT [768 x 8192] fp16
__global__ __launch_bounds__(256) void vt_kernel(const float* __restrict__ V,
                                                 unsigned short* __restrict__ vT) {
  __shared__ float t[32][33];
  const int bx = blockIdx.x, by = blockIdx.y;
  const int x = threadIdx.x, y = threadIdx.y;
#pragma unroll
  for (int r = 0; r < 4; ++r)
    t[y + r * 8][x] = V[(size_t)(by * 32 + y + r * 8) * 768 + bx * 32 + x];
  __syncthreads();
#pragma unroll
  for (int r = 0; r < 4; ++r)
    vT[(size_t)(bx * 32 + y + r * 8) * 8192 + by * 32 + x] = f2h(t[x][y + r * 8]);
}

// ---------------------------------------------------------------------------
extern "C" void kernel_launch(void* const* d_in, const int* in_sizes, int n_in,
                              void* d_out, int out_size, void* d_ws, size_t ws_size,
                              hipStream_t stream) {
  const int N = 8192, D = 768, DFF = 2048;
  const float* Q  = (const float*)d_in[0];
  const float* Km = (const float*)d_in[1];
  const float* V  = (const float*)d_in[2];
  const float* W1 = (const float*)d_in[3];
  const float* b1 = (const float*)d_in[4];
  const float* W2 = (const float*)d_in[5];
  const float* b2 = (const float*)d_in[6];

  char* w = (char*)d_ws;
  size_t off = 0;
  auto take = [&](size_t bytes) { void* p = w + off; off += bytes; return p; };
  unsigned short* qh   = (unsigned short*)take((size_t)N * D * 2);
  unsigned short* kh   = (unsigned short*)take((size_t)N * D * 2);
  unsigned short* vT   = (unsigned short*)take((size_t)N * D * 2);
  unsigned short* ctx16= (unsigned short*)take((size_t)N * D * 2);
  float*          ctx32= (float*)take((size_t)N * D * 4);
  unsigned short* hb   = (unsigned short*)take((size_t)N * DFF * 2);
  unsigned short* w1h  = (unsigned short*)take((size_t)DFF * D * 2);
  unsigned short* w2h  = (unsigned short*)take((size_t)D * DFF * 2);
  float*          stm  = (float*)take((size_t)64 * N * 4);
  float*          stl  = (float*)take((size_t)64 * N * 4);
  unsigned short* alp  = (unsigned short*)take((size_t)64 * N * 2);  // [tile][row]
  unsigned short* Pp   = (unsigned short*)take((size_t)N * N * 2);   // P' fp16, 128 MB
  (void)ws_size;

  cvt_f16<<<(N * D) / 256, 256, 0, stream>>>(Q, qh, N * D);
  cvt_f16<<<(N * D) / 256, 256, 0, stream>>>(Km, kh, N * D);
  vt_kernel<<<dim3(D / 32, N / 32), dim3(32, 8), 0, stream>>>(V, vT);
  cvt_f16<<<(DFF * D) / 256, 256, 0, stream>>>(W1, w1h, DFF * D);
  cvt_f16<<<(D * DFF) / 256, 256, 0, stream>>>(W2, w2h, D * DFF);
  hipMemsetAsync(ctx32, 0, (size_t)N * D * 4, stream);
  bias_fill<<<(N * D) / 256, 256, 0, stream>>>((float*)d_out, b2, D);

  {  // QK^T 256^2 8-phase with fused exp + per-(row,128-tile) stats
    hipFuncSetAttribute((const void*)qk256,
                        hipFuncAttributeMaxDynamicSharedMemorySize, 131072);
    qk256<<<(N / 256) * (N / 256), 512, 131072, stream>>>(
        qh, kh, Pp, stm, stl, N, D, D, D, N);
  }
  combine_alpha<<<N / 4, 256, 0, stream>>>(stm, stl, alp, 64, N);

  {  // ctx32 += (alphaT .* P') . V — 256x192, sl=2, grid 256 = 1/CU, atomics
    const int nt = D / 192, mt = N / 256, sl = 2;   // 4 x 32 x 2 = 256 blocks
    constexpr int BUFSZ = 32768 + 192 * 128;
    const int smem_sz = 2 * BUFSZ + ((N / 2) >> 7) * 256 * 2;  // 131072
    hipFuncSetAttribute((const void*)gemm256<192, 2, false, false, true, true>,
                        hipFuncAttributeMaxDynamicSharedMemorySize, smem_sz);
    gemm256<192, 2, false, false, true, true><<<nt * mt * sl, 512, smem_sz, stream>>>(
        Pp, vT, ctx32, nullptr, alp, N,
        N / sl, N, N, D, nt, mt, sl);
  }
  cvt_f16<<<(N * D) / 256, 256, 0, stream>>>(ctx32, ctx16, N * D);

  {  // h = relu(ctx . W1^T + b1)  fp16 — 256x256, grid 256 (verified R3)
    const int nt = DFF / 256, mt = N / 256;
    hipFuncSetAttribute((const void*)gemm256<256, 0, true, true, false, true>,
                        hipFuncAttributeMaxDynamicSharedMemorySize, 131072);
    gemm256<256, 0, true, true, false, true><<<nt * mt, 512, 131072, stream>>>(
        ctx16, w1h, hb, b1, nullptr, N,
        D, D, D, DFF, nt, mt, 1);
  }
  {  // out += h . W2^T  (bias pre-filled) — 256x192, sl=2, grid 256, atomics
    const int nt = D / 192, mt = N / 256, sl = 2;
    constexpr int BUFSZ = 32768 + 192 * 128;
    hipFuncSetAttribute((const void*)gemm256<192, 2, false, false, false, true>,
                        hipFuncAttributeMaxDynamicSharedMemorySize, 2 * BUFSZ);
    gemm256<192, 2, false, false, false, true><<<nt * mt * sl, 512, 2 * BUFSZ, stream>>>(
        hb, w2h, (float*)d_out, nullptr, nullptr, N,
        DFF / sl, DFF, DFF, D, nt, mt, sl);
  }
}

// Round 6
// 552.383 us; speedup vs baseline: 1.1903x; 1.0016x over previous
//
#include <hip/hip_runtime.h>
#include <cstdint>
#include <cstddef>

#define DEV __device__ __forceinline__

typedef _Float16 f16;
typedef __attribute__((ext_vector_type(8))) _Float16 f16x8;
typedef __attribute__((ext_vector_type(4))) float f32x4;

DEV unsigned short f2h(float f) {
  f16 h = (f16)f;
  return __builtin_bit_cast(unsigned short, h);
}

DEV void async_ld16(const void* g, void* l) {
  __builtin_amdgcn_global_load_lds(
      (__attribute__((address_space(1))) unsigned int*)(uintptr_t)g,
      (__attribute__((address_space(3))) unsigned int*)(uint32_t)(uintptr_t)l,
      16, 0, 0);
}

#define MFMA16(d, a, b_) (d) = __builtin_amdgcn_mfma_f32_16x16x32_f16((a), (b_), (d), 0, 0, 0)

// ---------------------------------------------------------------------------
// gemm256: C[M x N] = A[M x K] * B[N x K]^T  (K-contiguous, f16-as-ushort)
// 256xBN tile (BN in {256,192}), BK=64, 8 waves (2Mx4N), 8-phase pipeline
// (schedule verified R1-R3; BN=192 verified R5).
//   per-tile loads/thread: BN=256 -> 8 (A 2+2, B 2+2); BN=192 -> 7 (B1 = 1).
//   Both: end-of-tile outstanding = A0+B0+A1 of T+2 = 6 -> vmcnt(6) unchanged.
// B region mapping (within-region row rb -> global B row g):
//   BN=256: g = (rb/32)*64 + h*32 + rb%32      (each half = 2 x 8KB units)
//   BN=192 h=0: g = (u*2 + rr/32)*48 + rr%32   (2 units; feeds bv j=0,1)
//   BN=192 h=1: g = (rr/16)*48 + 32 + rr%16    (1 unit;  feeds bv j=2)
// EPI: 0 = fp16 store (+bias/relu), 2 = fp32 atomicAdd.
// ALPHA: alphaT[(K/128) x 256] slice staged to LDS annex at 2*BUFSZ,
// scales av0 at phase0 / av1 at phase2.
// XCD: per-XCD nb-inner placement (A-panel sharers co-resident on one XCD);
// requires mt%8==0, grid == nt*mt*sl.
// ---------------------------------------------------------------------------
template <int BN, int EPI, bool RELU, bool HASBIAS, bool ALPHA, bool XCD>
__global__ __launch_bounds__(512, 2) void gemm256(
    const unsigned short* __restrict__ A, const unsigned short* __restrict__ B,
    void* __restrict__ Cp, const float* __restrict__ bias,
    const unsigned short* __restrict__ alp, int Mtot,
    int K, int lda, int ldb, int ldc, int nt, int mt, int sl) {
  extern __shared__ char smem[];
  constexpr int FN = BN / 64;              // 4 or 3
  constexpr int WCW = BN / 4;              // per-wave col width: 64 or 48
  constexpr int BUFSZ = 32768 + BN * 128;  // A 32KB + B (32 or 24 KB)
  const int NT = K >> 6;

  int mb, nb, zb;
  {
    const int b = blockIdx.x;
    if (XCD) {
      const int xcd = b & 7, q = b >> 3;
      nb = q % nt;
      const int rest = q / nt;
      zb = rest % sl;
      mb = xcd * (mt >> 3) + rest / sl;
    } else {
      nb = b % nt;
      const int t = b / nt;
      mb = t % mt;
      zb = t / mt;
    }
  }
  const int bm = mb << 8, bn = nb * BN;
  const unsigned koff = (unsigned)zb * (unsigned)K;

  const int tid = threadIdx.x;
  const int wave = tid >> 6, lane = tid & 63;
  const int wr = wave >> 2, wc = wave & 3;   // wave grid 2 x 4
  const int mr = lane & 15, quad = lane >> 4;

  const int slot = tid & 7, rr = tid >> 3;
  const int ce = (slot ^ (rr & 7)) << 3;     // inverse-swizzled global col (x8 f16)

  f32x4 acc[8][FN] = {};
  f16x8 av0[4][2], av1[4][2], bv0[2][2], bv1[FN - 2][2];
  const f16* alb = (const f16*)(smem + 2 * BUFSZ);

  if (ALPHA) {
    const int ntl = K >> 7;
    const unsigned short* g0 = alp + (size_t)(zb * ntl) * Mtot + bm;
    uint4* s = (uint4*)(smem + 2 * BUFSZ);
    const int nu4 = (ntl << 5);
    for (int idx = tid; idx < nu4; idx += 512) {
      const int tt = idx >> 5;
      const int ru = (idx & 31) << 3;
      s[idx] = *(const uint4*)(g0 + (size_t)tt * Mtot + ru);
    }
  }

  auto stA = [&](int h, int Ts) {
    const int t_ = Ts >= NT ? Ts - NT : Ts;  // tail wrap: keep vmcnt ledger
    const unsigned kk = koff + (unsigned)(t_ << 6);
    char* l = smem + (Ts & 1) * BUFSZ + h * 16384 + wave * 1024;
#pragma unroll
    for (int p = 0; p < 2; ++p) {
      const unsigned off = (unsigned)(bm + p * 128 + h * 64 + rr) * (unsigned)lda + kk + ce;
      async_ld16(A + off, l + p * 8192);
    }
  };
  auto stB = [&](int h, int Ts) {
    const int t_ = Ts >= NT ? Ts - NT : Ts;
    const unsigned kk = koff + (unsigned)(t_ << 6);
    char* l = smem + (Ts & 1) * BUFSZ + 32768 + h * 16384 + wave * 1024;
    if (BN == 256) {
#pragma unroll
      for (int p = 0; p < 2; ++p) {
        const int g = bn + p * 128 + (rr >> 5) * 64 + h * 32 + (rr & 31);
        async_ld16(B + ((unsigned)g * (unsigned)ldb + kk + ce), l + p * 8192);
      }
    } else if (h == 0) {
#pragma unroll
      for (int p = 0; p < 2; ++p) {
        const int g = bn + (p * 2 + (rr >> 5)) * 48 + (rr & 31);
        async_ld16(B + ((unsigned)g * (unsigned)ldb + kk + ce), l + p * 8192);
      }
    } else {
      const int g = bn + (rr >> 4) * 48 + 32 + (rr & 15);
      async_ld16(B + ((unsigned)g * (unsigned)ldb + kk + ce), l);
    }
  };
  auto rdA = [&](int bufc, int i, int ks) {
    const int r = wr * 64 + (i & 3) * 16 + mr;   // r&7 == mr&7
    return *(const f16x8*)(smem + bufc + (i >> 2) * 16384 + r * 128 +
                           ((((ks << 2) | quad) ^ (mr & 7)) << 4));
  };
  auto rdB0 = [&](int bufc, int j, int ks) {   // half0: j = 0,1
    const int rb = wc * 32 + j * 16 + mr;      // rb&7 == mr&7
    return *(const f16x8*)(smem + bufc + 32768 + rb * 128 +
                           ((((ks << 2) | quad) ^ (mr & 7)) << 4));
  };
  auto rdB1 = [&](int bufc, int j, int ks) {   // half1: j = 2..FN-1
    const int rb = (BN == 256) ? (wc * 32 + (j - 2) * 16 + mr) : (wc * 16 + mr);
    return *(const f16x8*)(smem + bufc + 32768 + 16384 + rb * 128 +
                           ((((ks << 2) | quad) ^ (mr & 7)) << 4));
  };

  // prologue: stage tile0 (A0,B0,A1,B1) + tile1 (A0,B0,A1); wait tile0 landed
  stA(0, 0); stB(0, 0); stA(1, 0); stB(1, 0);
  stA(0, 1); stB(0, 1); stA(1, 1);
  if (ALPHA) asm volatile("s_waitcnt lgkmcnt(0)" ::: "memory");
  asm volatile("s_waitcnt vmcnt(6)" ::: "memory");
  __builtin_amdgcn_s_barrier();

  for (int T = 0; T < NT; ++T) {
    const int bufc = (T & 1) * BUFSZ;
    f16 a0_[4], a1_[4];
    // ---- phase 0: read A-half0 (+alpha) | stage B1(T+1) | MFMA prev (4..7 x hi)
#pragma unroll
    for (int i = 0; i < 4; ++i) { av0[i][0] = rdA(bufc, i, 0); av0[i][1] = rdA(bufc, i, 1); }
    if (ALPHA) {
#pragma unroll
      for (int i = 0; i < 4; ++i) a0_[i] = alb[(T >> 1) * 256 + wr * 128 + i * 16 + mr];
    }
    stB(1, T + 1);
    __builtin_amdgcn_s_barrier();
    asm volatile("s_waitcnt lgkmcnt(0)" ::: "memory");
    __builtin_amdgcn_sched_barrier(0);
    if (ALPHA) {
#pragma unroll
      for (int i = 0; i < 4; ++i) { av0[i][0] = av0[i][0] * a0_[i]; av0[i][1] = av0[i][1] * a0_[i]; }
    }
    if (T) {
      __builtin_amdgcn_s_setprio(1);
#pragma unroll
      for (int i = 0; i < 4; ++i)
#pragma unroll
        for (int j = 0; j < FN - 2; ++j) {
          MFMA16(acc[4 + i][2 + j], av1[i][0], bv1[j][0]);
          MFMA16(acc[4 + i][2 + j], av1[i][1], bv1[j][1]);
        }
      __builtin_amdgcn_s_setprio(0);
    }
    __builtin_amdgcn_s_barrier();
    // ---- phase 1: read B-half0 | stage A0(T+2) | MFMA (0..3 x 0..1)
#pragma unroll
    for (int j = 0; j < 2; ++j) { bv0[j][0] = rdB0(bufc, j, 0); bv0[j][1] = rdB0(bufc, j, 1); }
    stA(0, T + 2);
    __builtin_amdgcn_s_barrier();
    asm volatile("s_waitcnt lgkmcnt(0)" ::: "memory");
    __builtin_amdgcn_sched_barrier(0);
    __builtin_amdgcn_s_setprio(1);
#pragma unroll
    for (int i = 0; i < 4; ++i)
#pragma unroll
      for (int j = 0; j < 2; ++j) {
        MFMA16(acc[i][j], av0[i][0], bv0[j][0]);
        MFMA16(acc[i][j], av0[i][1], bv0[j][1]);
      }
    __builtin_amdgcn_s_setprio(0);
    __builtin_amdgcn_s_barrier();
    // ---- phase 2: read A-half1 (+alpha) | stage B0(T+2) | MFMA (4..7 x 0..1)
#pragma unroll
    for (int i = 0; i < 4; ++i) { av1[i][0] = rdA(bufc, 4 + i, 0); av1[i][1] = rdA(bufc, 4 + i, 1); }
    if (ALPHA) {
#pragma unroll
      for (int i = 0; i < 4; ++i) a1_[i] = alb[(T >> 1) * 256 + wr * 128 + 64 + i * 16 + mr];
    }
    stB(0, T + 2);
    __builtin_amdgcn_s_barrier();
    asm volatile("s_waitcnt lgkmcnt(0)" ::: "memory");
    __builtin_amdgcn_sched_barrier(0);
    if (ALPHA) {
#pragma unroll
      for (int i = 0; i < 4; ++i) { av1[i][0] = av1[i][0] * a1_[i]; av1[i][1] = av1[i][1] * a1_[i]; }
    }
    __builtin_amdgcn_s_setprio(1);
#pragma unroll
    for (int i = 0; i < 4; ++i)
#pragma unroll
      for (int j = 0; j < 2; ++j) {
        MFMA16(acc[4 + i][j], av1[i][0], bv0[j][0]);
        MFMA16(acc[4 + i][j], av1[i][1], bv0[j][1]);
      }
    __builtin_amdgcn_s_setprio(0);
    __builtin_amdgcn_s_barrier();
    // ---- phase 3: read B-half1 | stage A1(T+2) | MFMA (0..3 x hi) | vmcnt(6)
#pragma unroll
    for (int j = 0; j < FN - 2; ++j) { bv1[j][0] = rdB1(bufc, 2 + j, 0); bv1[j][1] = rdB1(bufc, 2 + j, 1); }
    stA(1, T + 2);
    __builtin_amdgcn_s_barrier();
    asm volatile("s_waitcnt lgkmcnt(0)" ::: "memory");
    __builtin_amdgcn_sched_barrier(0);
    __builtin_amdgcn_s_setprio(1);
#pragma unroll
    for (int i = 0; i < 4; ++i)
#pragma unroll
      for (int j = 0; j < FN - 2; ++j) {
        MFMA16(acc[i][2 + j], av0[i][0], bv1[j][0]);
        MFMA16(acc[i][2 + j], av0[i][1], bv1[j][1]);
      }
    __builtin_amdgcn_s_setprio(0);
    asm volatile("s_waitcnt vmcnt(6)" ::: "memory");
    __builtin_amdgcn_s_barrier();
  }
  // final cross-tile cluster: (4..7 x hi) of tile NT-1
  __builtin_amdgcn_s_setprio(1);
#pragma unroll
  for (int i = 0; i < 4; ++i)
#pragma unroll
    for (int j = 0; j < FN - 2; ++j) {
      MFMA16(acc[4 + i][2 + j], av1[i][0], bv1[j][0]);
      MFMA16(acc[4 + i][2 + j], av1[i][1], bv1[j][1]);
    }
  __builtin_amdgcn_s_setprio(0);
  asm volatile("s_waitcnt vmcnt(0)" ::: "memory");
  __builtin_amdgcn_s_barrier();

  // ---- epilogue ---------------------------------------------------------
#pragma unroll
  for (int i = 0; i < 8; ++i) {
#pragma unroll
    for (int j = 0; j < FN; ++j) {
      const int col = bn + wc * WCW + j * 16 + mr;
      float bb = 0.f;
      if (HASBIAS) bb = bias[col];
#pragma unroll
      for (int r = 0; r < 4; ++r) {
        const int row = bm + wr * 128 + i * 16 + quad * 4 + r;
        float v = acc[i][j][r];
        if (HASBIAS) v += bb;
        if (RELU) v = fmaxf(v, 0.f);
        if (EPI == 2)
          atomicAdd(&((float*)Cp)[(size_t)row * ldc + col], v);
        else
          ((unsigned short*)Cp)[(size_t)row * ldc + col] = f2h(v);
      }
    }
  }
}

// ---------------------------------------------------------------------------
// qk256: S = Q·K^T with fused exp + per-(row,128-col-half) m/l stats.
// Schedule verified R1. R6: within-XCD block-order remix — 4 rounds of 32
// blocks/XCD; old order put all 32 mb (12 MB of Q-panels) concurrent on one
// 4 MB L2 (thrash -> 224 MB FETCH). New order: each round = 8 mb x 4 nb
// (3 MB Q + 1.5 MB K ~ L2), K-group identical across rounds (stays hot).
// Bijective per XCD: c=0..127 -> (round=c>>5, mbl=(c>>2)&7, nbl=c&3).
// ---------------------------------------------------------------------------
__global__ __launch_bounds__(512, 2) void qk256(
    const unsigned short* __restrict__ A, const unsigned short* __restrict__ B,
    unsigned short* __restrict__ P, float* __restrict__ stm,
    float* __restrict__ stl, int M, int K, int lda, int ldb, int ldc) {
  extern __shared__ char smem[];
  const int NT = K >> 6;

  const int b = blockIdx.x;
  const int xcd = b & 7, c = b >> 3;
  const int mb = ((c >> 5) << 3) | ((c >> 2) & 7);
  const int nb = (xcd << 2) | (c & 3);
  const int bm = mb << 8, bn = nb << 8;

  const int tid = threadIdx.x;
  const int wave = tid >> 6, lane = tid & 63;
  const int wr = wave >> 2, wc = wave & 3;
  const int mr = lane & 15, quad = lane >> 4;

  const int slot = tid & 7, rr = tid >> 3;
  const int ce = (slot ^ (rr & 7)) << 3;

  f32x4 acc[8][4] = {};
  f16x8 av0[4][2], av1[4][2], bv0[2][2], bv1[2][2];

  auto stA = [&](int h, int Ts) {
    const int t = Ts >= NT ? Ts - NT : Ts;
    const int kk = t << 6;
    char* l = smem + ((Ts & 1) << 16) + h * 16384 + wave * 1024;
#pragma unroll
    for (int p = 0; p < 2; ++p) {
      const unsigned off = (unsigned)(bm + p * 128 + h * 64 + rr) * (unsigned)lda + kk + ce;
      async_ld16(A + off, l + p * 8192);
    }
  };
  auto stB = [&](int h, int Ts) {
    const int t = Ts >= NT ? Ts - NT : Ts;
    const int kk = t << 6;
    char* l = smem + ((Ts & 1) << 16) + 32768 + h * 16384 + wave * 1024;
#pragma unroll
    for (int p = 0; p < 2; ++p) {
      const unsigned off =
          (unsigned)(bn + p * 128 + (rr >> 5) * 64 + h * 32 + (rr & 31)) * (unsigned)ldb + kk + ce;
      async_ld16(B + off, l + p * 8192);
    }
  };
  auto rdA = [&](int bufc, int i, int ks) {
    const int r = wr * 64 + (i & 3) * 16 + mr;
    return *(const f16x8*)(smem + bufc + (i >> 2) * 16384 + r * 128 +
                           ((((ks << 2) | quad) ^ (mr & 7)) << 4));
  };
  auto rdB = [&](int bufc, int j, int ks) {
    const int r = wc * 32 + (j & 1) * 16 + mr;
    return *(const f16x8*)(smem + bufc + 32768 + (j >> 1) * 16384 + r * 128 +
                           ((((ks << 2) | quad) ^ (mr & 7)) << 4));
  };

  stA(0, 0); stB(0, 0); stA(1, 0); stB(1, 0);
  stA(0, 1); stB(0, 1); stA(1, 1);
  asm volatile("s_waitcnt vmcnt(6)" ::: "memory");
  __builtin_amdgcn_s_barrier();

  for (int T = 0; T < NT; ++T) {
    const int bufc = (T & 1) << 16;
#pragma unroll
    for (int i = 0; i < 4; ++i) { av0[i][0] = rdA(bufc, i, 0); av0[i][1] = rdA(bufc, i, 1); }
    stB(1, T + 1);
    __builtin_amdgcn_s_barrier();
    asm volatile("s_waitcnt lgkmcnt(0)" ::: "memory");
    __builtin_amdgcn_sched_barrier(0);
    if (T) {
      __builtin_amdgcn_s_setprio(1);
#pragma unroll
      for (int i = 0; i < 4; ++i)
#pragma unroll
        for (int j = 0; j < 2; ++j) {
          MFMA16(acc[4 + i][2 + j], av1[i][0], bv1[j][0]);
          MFMA16(acc[4 + i][2 + j], av1[i][1], bv1[j][1]);
        }
      __builtin_amdgcn_s_setprio(0);
    }
    __builtin_amdgcn_s_barrier();
#pragma unroll
    for (int j = 0; j < 2; ++j) { bv0[j][0] = rdB(bufc, j, 0); bv0[j][1] = rdB(bufc, j, 1); }
    stA(0, T + 2);
    __builtin_amdgcn_s_barrier();
    asm volatile("s_waitcnt lgkmcnt(0)" ::: "memory");
    __builtin_amdgcn_sched_barrier(0);
    __builtin_amdgcn_s_setprio(1);
#pragma unroll
    for (int i = 0; i < 4; ++i)
#pragma unroll
      for (int j = 0; j < 2; ++j) {
        MFMA16(acc[i][j], av0[i][0], bv0[j][0]);
        MFMA16(acc[i][j], av0[i][1], bv0[j][1]);
      }
    __builtin_amdgcn_s_setprio(0);
    __builtin_amdgcn_s_barrier();
#pragma unroll
    for (int i = 0; i < 4; ++i) { av1[i][0] = rdA(bufc, 4 + i, 0); av1[i][1] = rdA(bufc, 4 + i, 1); }
    stB(0, T + 2);
    __builtin_amdgcn_s_barrier();
    asm volatile("s_waitcnt lgkmcnt(0)" ::: "memory");
    __builtin_amdgcn_sched_barrier(0);
    __builtin_amdgcn_s_setprio(1);
#pragma unroll
    for (int i = 0; i < 4; ++i)
#pragma unroll
      for (int j = 0; j < 2; ++j) {
        MFMA16(acc[4 + i][j], av1[i][0], bv0[j][0]);
        MFMA16(acc[4 + i][j], av1[i][1], bv0[j][1]);
      }
    __builtin_amdgcn_s_setprio(0);
    __builtin_amdgcn_s_barrier();
#pragma unroll
    for (int j = 0; j < 2; ++j) { bv1[j][0] = rdB(bufc, 2 + j, 0); bv1[j][1] = rdB(bufc, 2 + j, 1); }
    stA(1, T + 2);
    __builtin_amdgcn_s_barrier();
    asm volatile("s_waitcnt lgkmcnt(0)" ::: "memory");
    __builtin_amdgcn_sched_barrier(0);
    __builtin_amdgcn_s_setprio(1);
#pragma unroll
    for (int i = 0; i < 4; ++i)
#pragma unroll
      for (int j = 0; j < 2; ++j) {
        MFMA16(acc[i][2 + j], av0[i][0], bv1[j][0]);
        MFMA16(acc[i][2 + j], av0[i][1], bv1[j][1]);
      }
    __builtin_amdgcn_s_setprio(0);
    asm volatile("s_waitcnt vmcnt(6)" ::: "memory");
    __builtin_amdgcn_s_barrier();
  }
  __builtin_amdgcn_s_setprio(1);
#pragma unroll
  for (int i = 0; i < 4; ++i)
#pragma unroll
    for (int j = 0; j < 2; ++j) {
      MFMA16(acc[4 + i][2 + j], av1[i][0], bv1[j][0]);
      MFMA16(acc[4 + i][2 + j], av1[i][1], bv1[j][1]);
    }
  __builtin_amdgcn_s_setprio(0);
  asm volatile("s_waitcnt vmcnt(0)" ::: "memory");
  __builtin_amdgcn_s_barrier();

  float* sred = (float*)smem;
  float* ssum = (float*)(smem + 4096);
  const int hc = wc >> 1;
  float Mh[8][4];

#pragma unroll
  for (int i = 0; i < 8; ++i)
#pragma unroll
    for (int r = 0; r < 4; ++r) {
      float m = acc[i][0][r];
#pragma unroll
      for (int j = 1; j < 4; ++j) m = fmaxf(m, acc[i][j][r]);
      m = fmaxf(m, __shfl_xor(m, 1));
      m = fmaxf(m, __shfl_xor(m, 2));
      m = fmaxf(m, __shfl_xor(m, 4));
      m = fmaxf(m, __shfl_xor(m, 8));
      if (mr == 0) sred[(wr * 128 + i * 16 + quad * 4 + r) * 4 + wc] = m;
    }
  __syncthreads();
#pragma unroll
  for (int i = 0; i < 8; ++i)
#pragma unroll
    for (int r = 0; r < 4; ++r) {
      const int row_l = wr * 128 + i * 16 + quad * 4 + r;
      Mh[i][r] = fmaxf(sred[row_l * 4 + 2 * hc], sred[row_l * 4 + 2 * hc + 1]);
    }
#pragma unroll
  for (int i = 0; i < 8; ++i)
#pragma unroll
    for (int r = 0; r < 4; ++r) {
      const int row_l = wr * 128 + i * 16 + quad * 4 + r;
      float l = 0.f;
#pragma unroll
      for (int j = 0; j < 4; ++j) {
        const float e = __expf(acc[i][j][r] - Mh[i][r]);
        P[(size_t)(bm + row_l) * ldc + (bn + wc * 64 + j * 16 + mr)] = f2h(e);
        l += e;
      }
      l += __shfl_xor(l, 1);
      l += __shfl_xor(l, 2);
      l += __shfl_xor(l, 4);
      l += __shfl_xor(l, 8);
      if (mr == 0) ssum[row_l * 4 + wc] = l;
    }
  __syncthreads();
  if ((wc & 1) == 0 && mr == 0) {
#pragma unroll
    for (int i = 0; i < 8; ++i)
#pragma unroll
      for (int r = 0; r < 4; ++r) {
        const int row_l = wr * 128 + i * 16 + quad * 4 + r;
        const int tile = nb * 2 + hc;
        stm[(size_t)tile * M + bm + row_l] = Mh[i][r];
        stl[(size_t)tile * M + bm + row_l] =
            ssum[row_l * 4 + 2 * hc] + ssum[row_l * 4 + 2 * hc + 1];
      }
  }
}

// per-row combine: M = max_t m_t, L = sum_t l_t*exp(m_t-M)
__global__ __launch_bounds__(256) void combine_alpha(
    const float* __restrict__ stm, const float* __restrict__ stl,
    unsigned short* __restrict__ alp, int ntile, int Mtot) {
  const int row = blockIdx.x * 4 + (threadIdx.x >> 6);
  const int t = threadIdx.x & 63;
  float m = (t < ntile) ? stm[(size_t)t * Mtot + row] : -1e30f;
  float M = m;
#pragma unroll
  for (int o = 1; o < 64; o <<= 1) M = fmaxf(M, __shfl_xor(M, o));
  float l = (t < ntile) ? stl[(size_t)t * Mtot + row] : 0.f;
  float c = l * __expf(m - M);
#pragma unroll
  for (int o = 1; o < 64; o <<= 1) c += __shfl_xor(c, o);
  if (t < ntile) alp[(size_t)t * Mtot + row] = f2h(__expf(m - M) / c);
}

__global__ __launch_bounds__(256) void cvt_f16(const float* __restrict__ in,
                                               unsigned short* __restrict__ out, int n) {
  int i = blockIdx.x * 256 + threadIdx.x;
  if (i < n) out[i] = f2h(in[i]);
}

__global__ __launch_bounds__(256) void bias_fill(float* __restrict__ out,
                                                 const float* __restrict__ b, int d) {
  int i = blockIdx.x * 256 + threadIdx.x;
  out[i] = b[i % d];
}

// V [8192 x 768] fp32 -> vT [768 x 8192] fp16
__global__ __launch_bounds__(256) void vt_kernel(const float* __restrict__ V,
                                                 unsigned short* __restrict__ vT) {
  __shared__ float t[32][33];
  const int bx = blockIdx.x, by = blockIdx.y;
  const int x = threadIdx.x, y = threadIdx.y;
#pragma unroll
  for (int r = 0; r < 4; ++r)
    t[y + r * 8][x] = V[(size_t)(by * 32 + y + r * 8) * 768 + bx * 32 + x];
  __syncthreads();
#pragma unroll
  for (int r = 0; r < 4; ++r)
    vT[(size_t)(bx * 32 + y + r * 8) * 8192 + by * 32 + x] = f2h(t[x][y + r * 8]);
}

// ---------------------------------------------------------------------------
extern "C" void kernel_launch(void* const* d_in, const int* in_sizes, int n_in,
                              void* d_out, int out_size, void* d_ws, size_t ws_size,
                              hipStream_t stream) {
  const int N = 8192, D = 768, DFF = 2048;
  const float* Q  = (const float*)d_in[0];
  const float* Km = (const float*)d_in[1];
  const float* V  = (const float*)d_in[2];
  const float* W1 = (const float*)d_in[3];
  const float* b1 = (const float*)d_in[4];
  const float* W2 = (const float*)d_in[5];
  const float* b2 = (const float*)d_in[6];

  char* w = (char*)d_ws;
  size_t off = 0;
  auto take = [&](size_t bytes) { void* p = w + off; off += bytes; return p; };
  unsigned short* qh   = (unsigned short*)take((size_t)N * D * 2);
  unsigned short* kh   = (unsigned short*)take((size_t)N * D * 2);
  unsigned short* vT   = (unsigned short*)take((size_t)N * D * 2);
  unsigned short* ctx16= (unsigned short*)take((size_t)N * D * 2);
  float*          ctx32= (float*)take((size_t)N * D * 4);
  unsigned short* hb   = (unsigned short*)take((size_t)N * DFF * 2);
  unsigned short* w1h  = (unsigned short*)take((size_t)DFF * D * 2);
  unsigned short* w2h  = (unsigned short*)take((size_t)D * DFF * 2);
  float*          stm  = (float*)take((size_t)64 * N * 4);
  float*          stl  = (float*)take((size_t)64 * N * 4);
  unsigned short* alp  = (unsigned short*)take((size_t)64 * N * 2);  // [tile][row]
  unsigned short* Pp   = (unsigned short*)take((size_t)N * N * 2);   // P' fp16, 128 MB
  (void)ws_size;

  cvt_f16<<<(N * D) / 256, 256, 0, stream>>>(Q, qh, N * D);
  cvt_f16<<<(N * D) / 256, 256, 0, stream>>>(Km, kh, N * D);
  vt_kernel<<<dim3(D / 32, N / 32), dim3(32, 8), 0, stream>>>(V, vT);
  cvt_f16<<<(DFF * D) / 256, 256, 0, stream>>>(W1, w1h, DFF * D);
  cvt_f16<<<(D * DFF) / 256, 256, 0, stream>>>(W2, w2h, D * DFF);
  hipMemsetAsync(ctx32, 0, (size_t)N * D * 4, stream);
  bias_fill<<<(N * D) / 256, 256, 0, stream>>>((float*)d_out, b2, D);

  {  // QK^T 256^2 8-phase with fused exp + per-(row,128-tile) stats
    hipFuncSetAttribute((const void*)qk256,
                        hipFuncAttributeMaxDynamicSharedMemorySize, 131072);
    qk256<<<(N / 256) * (N / 256), 512, 131072, stream>>>(
        qh, kh, Pp, stm, stl, N, D, D, D, N);
  }
  combine_alpha<<<N / 4, 256, 0, stream>>>(stm, stl, alp, 64, N);

  {  // ctx32 += (alphaT .* P') . V — 256x192, sl=2, grid 256 = 1/CU, atomics
    const int nt = D / 192, mt = N / 256, sl = 2;   // 4 x 32 x 2 = 256 blocks
    constexpr int BUFSZ = 32768 + 192 * 128;
    const int smem_sz = 2 * BUFSZ + ((N / 2) >> 7) * 256 * 2;  // 131072
    hipFuncSetAttribute((const void*)gemm256<192, 2, false, false, true, true>,
                        hipFuncAttributeMaxDynamicSharedMemorySize, smem_sz);
    gemm256<192, 2, false, false, true, true><<<nt * mt * sl, 512, smem_sz, stream>>>(
        Pp, vT, ctx32, nullptr, alp, N,
        N / sl, N, N, D, nt, mt, sl);
  }
  cvt_f16<<<(N * D) / 256, 256, 0, stream>>>(ctx32, ctx16, N * D);

  {  // h = relu(ctx . W1^T + b1)  fp16 — 256x256, grid 256 (verified R3)
    const int nt = DFF / 256, mt = N / 256;
    hipFuncSetAttribute((const void*)gemm256<256, 0, true, true, false, true>,
                        hipFuncAttributeMaxDynamicSharedMemorySize, 131072);
    gemm256<256, 0, true, true, false, true><<<nt * mt, 512, 131072, stream>>>(
        ctx16, w1h, hb, b1, nullptr, N,
        D, D, D, DFF, nt, mt, 1);
  }
  {  // out += h . W2^T  (bias pre-filled) — 256x192, sl=2, grid 256, atomics
    const int nt = D / 192, mt = N / 256, sl = 2;
    constexpr int BUFSZ = 32768 + 192 * 128;
    hipFuncSetAttribute((const void*)gemm256<192, 2, false, false, false, true>,
                        hipFuncAttributeMaxDynamicSharedMemorySize, 2 * BUFSZ);
    gemm256<192, 2, false, false, false, true><<<nt * mt * sl, 512, 2 * BUFSZ, stream>>>(
        hb, w2h, (float*)d_out, nullptr, nullptr, N,
        DFF / sl, DFF, DFF, D, nt, mt, sl);
  }
}

// Round 7
// 480.640 us; speedup vs baseline: 1.3679x; 1.1493x over previous
//
#include <hip/hip_runtime.h>
#include <cstdint>
#include <cstddef>

#define DEV __device__ __forceinline__

typedef _Float16 f16;
typedef __attribute__((ext_vector_type(8))) _Float16 f16x8;
typedef __attribute__((ext_vector_type(4))) float f32x4;
typedef __attribute__((ext_vector_type(4))) unsigned short us4;

DEV unsigned short f2h(float f) {
  f16 h = (f16)f;
  return __builtin_bit_cast(unsigned short, h);
}

DEV void async_ld16(const void* g, void* l) {
  __builtin_amdgcn_global_load_lds(
      (__attribute__((address_space(1))) unsigned int*)(uintptr_t)g,
      (__attribute__((address_space(3))) unsigned int*)(uint32_t)(uintptr_t)l,
      16, 0, 0);
}

#define MFMA16(d, a, b_) (d) = __builtin_amdgcn_mfma_f32_16x16x32_f16((a), (b_), (d), 0, 0, 0)

// ---------------------------------------------------------------------------
// gemm256: C[M x N] = A[M x K] * B[N x K]^T  (K-contiguous, f16-as-ushort)
// 256xBN tile (BN in {256,192}), BK=64, 8 waves (2Mx4N), 8-phase pipeline
// (schedule verified R1-R3; BN=192 verified R5).
//   per-tile loads/thread: BN=256 -> 8 (A 2+2, B 2+2); BN=192 -> 7 (B1 = 1).
//   Both: end-of-tile outstanding = A0+B0+A1 of T+2 = 6 -> vmcnt(6) unchanged.
// B region mapping (within-region row rb -> global B row g):
//   BN=256: g = (rb/32)*64 + h*32 + rb%32      (each half = 2 x 8KB units)
//   BN=192 h=0: g = (u*2 + rr/32)*48 + rr%32   (2 units; feeds bv j=0,1)
//   BN=192 h=1: g = (rr/16)*48 + 32 + rr%16    (1 unit;  feeds bv j=2)
// EPI: 0 = fp16 store (+bias/relu), 1 = fp32 shard store at Cp + zb*Mtot*ldc,
//      2 = fp32 atomicAdd (legacy).
// ALPHA: alphaT[(K/128) x 256] slice staged to LDS annex at 2*BUFSZ,
// scales av0 at phase0 / av1 at phase2.
// XCD: per-XCD nb-inner placement (A-panel sharers co-resident on one XCD);
// requires mt%8==0, grid == nt*mt*sl.
// ---------------------------------------------------------------------------
template <int BN, int EPI, bool RELU, bool HASBIAS, bool ALPHA, bool XCD>
__global__ __launch_bounds__(512, 2) void gemm256(
    const unsigned short* __restrict__ A, const unsigned short* __restrict__ B,
    void* __restrict__ Cp, const float* __restrict__ bias,
    const unsigned short* __restrict__ alp, int Mtot,
    int K, int lda, int ldb, int ldc, int nt, int mt, int sl) {
  extern __shared__ char smem[];
  constexpr int FN = BN / 64;              // 4 or 3
  constexpr int WCW = BN / 4;              // per-wave col width: 64 or 48
  constexpr int BUFSZ = 32768 + BN * 128;  // A 32KB + B (32 or 24 KB)
  const int NT = K >> 6;

  int mb, nb, zb;
  {
    const int b = blockIdx.x;
    if (XCD) {
      const int xcd = b & 7, q = b >> 3;
      nb = q % nt;
      const int rest = q / nt;
      zb = rest % sl;
      mb = xcd * (mt >> 3) + rest / sl;
    } else {
      nb = b % nt;
      const int t = b / nt;
      mb = t % mt;
      zb = t / mt;
    }
  }
  const int bm = mb << 8, bn = nb * BN;
  const unsigned koff = (unsigned)zb * (unsigned)K;

  const int tid = threadIdx.x;
  const int wave = tid >> 6, lane = tid & 63;
  const int wr = wave >> 2, wc = wave & 3;   // wave grid 2 x 4
  const int mr = lane & 15, quad = lane >> 4;

  const int slot = tid & 7, rr = tid >> 3;
  const int ce = (slot ^ (rr & 7)) << 3;     // inverse-swizzled global col (x8 f16)

  f32x4 acc[8][FN] = {};
  f16x8 av0[4][2], av1[4][2], bv0[2][2], bv1[FN - 2][2];
  const f16* alb = (const f16*)(smem + 2 * BUFSZ);

  if (ALPHA) {
    const int ntl = K >> 7;
    const unsigned short* g0 = alp + (size_t)(zb * ntl) * Mtot + bm;
    uint4* s = (uint4*)(smem + 2 * BUFSZ);
    const int nu4 = (ntl << 5);
    for (int idx = tid; idx < nu4; idx += 512) {
      const int tt = idx >> 5;
      const int ru = (idx & 31) << 3;
      s[idx] = *(const uint4*)(g0 + (size_t)tt * Mtot + ru);
    }
  }

  auto stA = [&](int h, int Ts) {
    const int t_ = Ts >= NT ? Ts - NT : Ts;  // tail wrap: keep vmcnt ledger
    const unsigned kk = koff + (unsigned)(t_ << 6);
    char* l = smem + (Ts & 1) * BUFSZ + h * 16384 + wave * 1024;
#pragma unroll
    for (int p = 0; p < 2; ++p) {
      const unsigned off = (unsigned)(bm + p * 128 + h * 64 + rr) * (unsigned)lda + kk + ce;
      async_ld16(A + off, l + p * 8192);
    }
  };
  auto stB = [&](int h, int Ts) {
    const int t_ = Ts >= NT ? Ts - NT : Ts;
    const unsigned kk = koff + (unsigned)(t_ << 6);
    char* l = smem + (Ts & 1) * BUFSZ + 32768 + h * 16384 + wave * 1024;
    if (BN == 256) {
#pragma unroll
      for (int p = 0; p < 2; ++p) {
        const int g = bn + p * 128 + (rr >> 5) * 64 + h * 32 + (rr & 31);
        async_ld16(B + ((unsigned)g * (unsigned)ldb + kk + ce), l + p * 8192);
      }
    } else if (h == 0) {
#pragma unroll
      for (int p = 0; p < 2; ++p) {
        const int g = bn + (p * 2 + (rr >> 5)) * 48 + (rr & 31);
        async_ld16(B + ((unsigned)g * (unsigned)ldb + kk + ce), l + p * 8192);
      }
    } else {
      const int g = bn + (rr >> 4) * 48 + 32 + (rr & 15);
      async_ld16(B + ((unsigned)g * (unsigned)ldb + kk + ce), l);
    }
  };
  auto rdA = [&](int bufc, int i, int ks) {
    const int r = wr * 64 + (i & 3) * 16 + mr;   // r&7 == mr&7
    return *(const f16x8*)(smem + bufc + (i >> 2) * 16384 + r * 128 +
                           ((((ks << 2) | quad) ^ (mr & 7)) << 4));
  };
  auto rdB0 = [&](int bufc, int j, int ks) {   // half0: j = 0,1
    const int rb = wc * 32 + j * 16 + mr;      // rb&7 == mr&7
    return *(const f16x8*)(smem + bufc + 32768 + rb * 128 +
                           ((((ks << 2) | quad) ^ (mr & 7)) << 4));
  };
  auto rdB1 = [&](int bufc, int j, int ks) {   // half1: j = 2..FN-1
    const int rb = (BN == 256) ? (wc * 32 + (j - 2) * 16 + mr) : (wc * 16 + mr);
    return *(const f16x8*)(smem + bufc + 32768 + 16384 + rb * 128 +
                           ((((ks << 2) | quad) ^ (mr & 7)) << 4));
  };

  // prologue: stage tile0 (A0,B0,A1,B1) + tile1 (A0,B0,A1); wait tile0 landed
  stA(0, 0); stB(0, 0); stA(1, 0); stB(1, 0);
  stA(0, 1); stB(0, 1); stA(1, 1);
  if (ALPHA) asm volatile("s_waitcnt lgkmcnt(0)" ::: "memory");
  asm volatile("s_waitcnt vmcnt(6)" ::: "memory");
  __builtin_amdgcn_s_barrier();

  for (int T = 0; T < NT; ++T) {
    const int bufc = (T & 1) * BUFSZ;
    f16 a0_[4], a1_[4];
    // ---- phase 0: read A-half0 (+alpha) | stage B1(T+1) | MFMA prev (4..7 x hi)
#pragma unroll
    for (int i = 0; i < 4; ++i) { av0[i][0] = rdA(bufc, i, 0); av0[i][1] = rdA(bufc, i, 1); }
    if (ALPHA) {
#pragma unroll
      for (int i = 0; i < 4; ++i) a0_[i] = alb[(T >> 1) * 256 + wr * 128 + i * 16 + mr];
    }
    stB(1, T + 1);
    __builtin_amdgcn_s_barrier();
    asm volatile("s_waitcnt lgkmcnt(0)" ::: "memory");
    __builtin_amdgcn_sched_barrier(0);
    if (ALPHA) {
#pragma unroll
      for (int i = 0; i < 4; ++i) { av0[i][0] = av0[i][0] * a0_[i]; av0[i][1] = av0[i][1] * a0_[i]; }
    }
    if (T) {
      __builtin_amdgcn_s_setprio(1);
#pragma unroll
      for (int i = 0; i < 4; ++i)
#pragma unroll
        for (int j = 0; j < FN - 2; ++j) {
          MFMA16(acc[4 + i][2 + j], av1[i][0], bv1[j][0]);
          MFMA16(acc[4 + i][2 + j], av1[i][1], bv1[j][1]);
        }
      __builtin_amdgcn_s_setprio(0);
    }
    __builtin_amdgcn_s_barrier();
    // ---- phase 1: read B-half0 | stage A0(T+2) | MFMA (0..3 x 0..1)
#pragma unroll
    for (int j = 0; j < 2; ++j) { bv0[j][0] = rdB0(bufc, j, 0); bv0[j][1] = rdB0(bufc, j, 1); }
    stA(0, T + 2);
    __builtin_amdgcn_s_barrier();
    asm volatile("s_waitcnt lgkmcnt(0)" ::: "memory");
    __builtin_amdgcn_sched_barrier(0);
    __builtin_amdgcn_s_setprio(1);
#pragma unroll
    for (int i = 0; i < 4; ++i)
#pragma unroll
      for (int j = 0; j < 2; ++j) {
        MFMA16(acc[i][j], av0[i][0], bv0[j][0]);
        MFMA16(acc[i][j], av0[i][1], bv0[j][1]);
      }
    __builtin_amdgcn_s_setprio(0);
    __builtin_amdgcn_s_barrier();
    // ---- phase 2: read A-half1 (+alpha) | stage B0(T+2) | MFMA (4..7 x 0..1)
#pragma unroll
    for (int i = 0; i < 4; ++i) { av1[i][0] = rdA(bufc, 4 + i, 0); av1[i][1] = rdA(bufc, 4 + i, 1); }
    if (ALPHA) {
#pragma unroll
      for (int i = 0; i < 4; ++i) a1_[i] = alb[(T >> 1) * 256 + wr * 128 + 64 + i * 16 + mr];
    }
    stB(0, T + 2);
    __builtin_amdgcn_s_barrier();
    asm volatile("s_waitcnt lgkmcnt(0)" ::: "memory");
    __builtin_amdgcn_sched_barrier(0);
    if (ALPHA) {
#pragma unroll
      for (int i = 0; i < 4; ++i) { av1[i][0] = av1[i][0] * a1_[i]; av1[i][1] = av1[i][1] * a1_[i]; }
    }
    __builtin_amdgcn_s_setprio(1);
#pragma unroll
    for (int i = 0; i < 4; ++i)
#pragma unroll
      for (int j = 0; j < 2; ++j) {
        MFMA16(acc[4 + i][j], av1[i][0], bv0[j][0]);
        MFMA16(acc[4 + i][j], av1[i][1], bv0[j][1]);
      }
    __builtin_amdgcn_s_setprio(0);
    __builtin_amdgcn_s_barrier();
    // ---- phase 3: read B-half1 | stage A1(T+2) | MFMA (0..3 x hi) | vmcnt(6)
#pragma unroll
    for (int j = 0; j < FN - 2; ++j) { bv1[j][0] = rdB1(bufc, 2 + j, 0); bv1[j][1] = rdB1(bufc, 2 + j, 1); }
    stA(1, T + 2);
    __builtin_amdgcn_s_barrier();
    asm volatile("s_waitcnt lgkmcnt(0)" ::: "memory");
    __builtin_amdgcn_sched_barrier(0);
    __builtin_amdgcn_s_setprio(1);
#pragma unroll
    for (int i = 0; i < 4; ++i)
#pragma unroll
      for (int j = 0; j < FN - 2; ++j) {
        MFMA16(acc[i][2 + j], av0[i][0], bv1[j][0]);
        MFMA16(acc[i][2 + j], av0[i][1], bv1[j][1]);
      }
    __builtin_amdgcn_s_setprio(0);
    asm volatile("s_waitcnt vmcnt(6)" ::: "memory");
    __builtin_amdgcn_s_barrier();
  }
  // final cross-tile cluster: (4..7 x hi) of tile NT-1
  __builtin_amdgcn_s_setprio(1);
#pragma unroll
  for (int i = 0; i < 4; ++i)
#pragma unroll
    for (int j = 0; j < FN - 2; ++j) {
      MFMA16(acc[4 + i][2 + j], av1[i][0], bv1[j][0]);
      MFMA16(acc[4 + i][2 + j], av1[i][1], bv1[j][1]);
    }
  __builtin_amdgcn_s_setprio(0);
  asm volatile("s_waitcnt vmcnt(0)" ::: "memory");
  __builtin_amdgcn_s_barrier();

  // ---- epilogue ---------------------------------------------------------
#pragma unroll
  for (int i = 0; i < 8; ++i) {
#pragma unroll
    for (int j = 0; j < FN; ++j) {
      const int col = bn + wc * WCW + j * 16 + mr;
      float bb = 0.f;
      if (HASBIAS) bb = bias[col];
#pragma unroll
      for (int r = 0; r < 4; ++r) {
        const int row = bm + wr * 128 + i * 16 + quad * 4 + r;
        float v = acc[i][j][r];
        if (HASBIAS) v += bb;
        if (RELU) v = fmaxf(v, 0.f);
        if (EPI == 2)
          atomicAdd(&((float*)Cp)[(size_t)row * ldc + col], v);
        else if (EPI == 1)
          ((float*)Cp)[(size_t)zb * Mtot * ldc + (size_t)row * ldc + col] = v;
        else
          ((unsigned short*)Cp)[(size_t)row * ldc + col] = f2h(v);
      }
    }
  }
}

// ---------------------------------------------------------------------------
// qk256: S = Q·K^T with fused exp + per-(row,128-col-half) m/l stats.
// Schedule verified R1; R6 L2 block-order remix kept.
// ---------------------------------------------------------------------------
__global__ __launch_bounds__(512, 2) void qk256(
    const unsigned short* __restrict__ A, const unsigned short* __restrict__ B,
    unsigned short* __restrict__ P, float* __restrict__ stm,
    float* __restrict__ stl, int M, int K, int lda, int ldb, int ldc) {
  extern __shared__ char smem[];
  const int NT = K >> 6;

  const int b = blockIdx.x;
  const int xcd = b & 7, c = b >> 3;
  const int mb = ((c >> 5) << 3) | ((c >> 2) & 7);
  const int nb = (xcd << 2) | (c & 3);
  const int bm = mb << 8, bn = nb << 8;

  const int tid = threadIdx.x;
  const int wave = tid >> 6, lane = tid & 63;
  const int wr = wave >> 2, wc = wave & 3;
  const int mr = lane & 15, quad = lane >> 4;

  const int slot = tid & 7, rr = tid >> 3;
  const int ce = (slot ^ (rr & 7)) << 3;

  f32x4 acc[8][4] = {};
  f16x8 av0[4][2], av1[4][2], bv0[2][2], bv1[2][2];

  auto stA = [&](int h, int Ts) {
    const int t = Ts >= NT ? Ts - NT : Ts;
    const int kk = t << 6;
    char* l = smem + ((Ts & 1) << 16) + h * 16384 + wave * 1024;
#pragma unroll
    for (int p = 0; p < 2; ++p) {
      const unsigned off = (unsigned)(bm + p * 128 + h * 64 + rr) * (unsigned)lda + kk + ce;
      async_ld16(A + off, l + p * 8192);
    }
  };
  auto stB = [&](int h, int Ts) {
    const int t = Ts >= NT ? Ts - NT : Ts;
    const int kk = t << 6;
    char* l = smem + ((Ts & 1) << 16) + 32768 + h * 16384 + wave * 1024;
#pragma unroll
    for (int p = 0; p < 2; ++p) {
      const unsigned off =
          (unsigned)(bn + p * 128 + (rr >> 5) * 64 + h * 32 + (rr & 31)) * (unsigned)ldb + kk + ce;
      async_ld16(B + off, l + p * 8192);
    }
  };
  auto rdA = [&](int bufc, int i, int ks) {
    const int r = wr * 64 + (i & 3) * 16 + mr;
    return *(const f16x8*)(smem + bufc + (i >> 2) * 16384 + r * 128 +
                           ((((ks << 2) | quad) ^ (mr & 7)) << 4));
  };
  auto rdB = [&](int bufc, int j, int ks) {
    const int r = wc * 32 + (j & 1) * 16 + mr;
    return *(const f16x8*)(smem + bufc + 32768 + (j >> 1) * 16384 + r * 128 +
                           ((((ks << 2) | quad) ^ (mr & 7)) << 4));
  };

  stA(0, 0); stB(0, 0); stA(1, 0); stB(1, 0);
  stA(0, 1); stB(0, 1); stA(1, 1);
  asm volatile("s_waitcnt vmcnt(6)" ::: "memory");
  __builtin_amdgcn_s_barrier();

  for (int T = 0; T < NT; ++T) {
    const int bufc = (T & 1) << 16;
#pragma unroll
    for (int i = 0; i < 4; ++i) { av0[i][0] = rdA(bufc, i, 0); av0[i][1] = rdA(bufc, i, 1); }
    stB(1, T + 1);
    __builtin_amdgcn_s_barrier();
    asm volatile("s_waitcnt lgkmcnt(0)" ::: "memory");
    __builtin_amdgcn_sched_barrier(0);
    if (T) {
      __builtin_amdgcn_s_setprio(1);
#pragma unroll
      for (int i = 0; i < 4; ++i)
#pragma unroll
        for (int j = 0; j < 2; ++j) {
          MFMA16(acc[4 + i][2 + j], av1[i][0], bv1[j][0]);
          MFMA16(acc[4 + i][2 + j], av1[i][1], bv1[j][1]);
        }
      __builtin_amdgcn_s_setprio(0);
    }
    __builtin_amdgcn_s_barrier();
#pragma unroll
    for (int j = 0; j < 2; ++j) { bv0[j][0] = rdB(bufc, j, 0); bv0[j][1] = rdB(bufc, j, 1); }
    stA(0, T + 2);
    __builtin_amdgcn_s_barrier();
    asm volatile("s_waitcnt lgkmcnt(0)" ::: "memory");
    __builtin_amdgcn_sched_barrier(0);
    __builtin_amdgcn_s_setprio(1);
#pragma unroll
    for (int i = 0; i < 4; ++i)
#pragma unroll
      for (int j = 0; j < 2; ++j) {
        MFMA16(acc[i][j], av0[i][0], bv0[j][0]);
        MFMA16(acc[i][j], av0[i][1], bv0[j][1]);
      }
    __builtin_amdgcn_s_setprio(0);
    __builtin_amdgcn_s_barrier();
#pragma unroll
    for (int i = 0; i < 4; ++i) { av1[i][0] = rdA(bufc, 4 + i, 0); av1[i][1] = rdA(bufc, 4 + i, 1); }
    stB(0, T + 2);
    __builtin_amdgcn_s_barrier();
    asm volatile("s_waitcnt lgkmcnt(0)" ::: "memory");
    __builtin_amdgcn_sched_barrier(0);
    __builtin_amdgcn_s_setprio(1);
#pragma unroll
    for (int i = 0; i < 4; ++i)
#pragma unroll
      for (int j = 0; j < 2; ++j) {
        MFMA16(acc[4 + i][j], av1[i][0], bv0[j][0]);
        MFMA16(acc[4 + i][j], av1[i][1], bv0[j][1]);
      }
    __builtin_amdgcn_s_setprio(0);
    __builtin_amdgcn_s_barrier();
#pragma unroll
    for (int j = 0; j < 2; ++j) { bv1[j][0] = rdB(bufc, 2 + j, 0); bv1[j][1] = rdB(bufc, 2 + j, 1); }
    stA(1, T + 2);
    __builtin_amdgcn_s_barrier();
    asm volatile("s_waitcnt lgkmcnt(0)" ::: "memory");
    __builtin_amdgcn_sched_barrier(0);
    __builtin_amdgcn_s_setprio(1);
#pragma unroll
    for (int i = 0; i < 4; ++i)
#pragma unroll
      for (int j = 0; j < 2; ++j) {
        MFMA16(acc[i][2 + j], av0[i][0], bv1[j][0]);
        MFMA16(acc[i][2 + j], av0[i][1], bv1[j][1]);
      }
    __builtin_amdgcn_s_setprio(0);
    asm volatile("s_waitcnt vmcnt(6)" ::: "memory");
    __builtin_amdgcn_s_barrier();
  }
  __builtin_amdgcn_s_setprio(1);
#pragma unroll
  for (int i = 0; i < 4; ++i)
#pragma unroll
    for (int j = 0; j < 2; ++j) {
      MFMA16(acc[4 + i][2 + j], av1[i][0], bv1[j][0]);
      MFMA16(acc[4 + i][2 + j], av1[i][1], bv1[j][1]);
    }
  __builtin_amdgcn_s_setprio(0);
  asm volatile("s_waitcnt vmcnt(0)" ::: "memory");
  __builtin_amdgcn_s_barrier();

  float* sred = (float*)smem;
  float* ssum = (float*)(smem + 4096);
  const int hc = wc >> 1;
  float Mh[8][4];

#pragma unroll
  for (int i = 0; i < 8; ++i)
#pragma unroll
    for (int r = 0; r < 4; ++r) {
      float m = acc[i][0][r];
#pragma unroll
      for (int j = 1; j < 4; ++j) m = fmaxf(m, acc[i][j][r]);
      m = fmaxf(m, __shfl_xor(m, 1));
      m = fmaxf(m, __shfl_xor(m, 2));
      m = fmaxf(m, __shfl_xor(m, 4));
      m = fmaxf(m, __shfl_xor(m, 8));
      if (mr == 0) sred[(wr * 128 + i * 16 + quad * 4 + r) * 4 + wc] = m;
    }
  __syncthreads();
#pragma unroll
  for (int i = 0; i < 8; ++i)
#pragma unroll
    for (int r = 0; r < 4; ++r) {
      const int row_l = wr * 128 + i * 16 + quad * 4 + r;
      Mh[i][r] = fmaxf(sred[row_l * 4 + 2 * hc], sred[row_l * 4 + 2 * hc + 1]);
    }
#pragma unroll
  for (int i = 0; i < 8; ++i)
#pragma unroll
    for (int r = 0; r < 4; ++r) {
      const int row_l = wr * 128 + i * 16 + quad * 4 + r;
      float l = 0.f;
#pragma unroll
      for (int j = 0; j < 4; ++j) {
        const float e = __expf(acc[i][j][r] - Mh[i][r]);
        P[(size_t)(bm + row_l) * ldc + (bn + wc * 64 + j * 16 + mr)] = f2h(e);
        l += e;
      }
      l += __shfl_xor(l, 1);
      l += __shfl_xor(l, 2);
      l += __shfl_xor(l, 4);
      l += __shfl_xor(l, 8);
      if (mr == 0) ssum[row_l * 4 + wc] = l;
    }
  __syncthreads();
  if ((wc & 1) == 0 && mr == 0) {
#pragma unroll
    for (int i = 0; i < 8; ++i)
#pragma unroll
      for (int r = 0; r < 4; ++r) {
        const int row_l = wr * 128 + i * 16 + quad * 4 + r;
        const int tile = nb * 2 + hc;
        stm[(size_t)tile * M + bm + row_l] = Mh[i][r];
        stl[(size_t)tile * M + bm + row_l] =
            ssum[row_l * 4 + 2 * hc] + ssum[row_l * 4 + 2 * hc + 1];
      }
  }
}

// per-row combine: M = max_t m_t, L = sum_t l_t*exp(m_t-M)
__global__ __launch_bounds__(256) void combine_alpha(
    const float* __restrict__ stm, const float* __restrict__ stl,
    unsigned short* __restrict__ alp, int ntile, int Mtot) {
  const int row = blockIdx.x * 4 + (threadIdx.x >> 6);
  const int t = threadIdx.x & 63;
  float m = (t < ntile) ? stm[(size_t)t * Mtot + row] : -1e30f;
  float M = m;
#pragma unroll
  for (int o = 1; o < 64; o <<= 1) M = fmaxf(M, __shfl_xor(M, o));
  float l = (t < ntile) ? stl[(size_t)t * Mtot + row] : 0.f;
  float c = l * __expf(m - M);
#pragma unroll
  for (int o = 1; o < 64; o <<= 1) c += __shfl_xor(c, o);
  if (t < ntile) alp[(size_t)t * Mtot + row] = f2h(__expf(m - M) / c);
}

// merged fp32->fp16 conversion for Q, K, W1, W2 (vectorized x4)
__global__ __launch_bounds__(256) void prep4(
    const float* __restrict__ Q, const float* __restrict__ Km,
    const float* __restrict__ W1, const float* __restrict__ W2,
    unsigned short* __restrict__ qh, unsigned short* __restrict__ kh,
    unsigned short* __restrict__ w1h, unsigned short* __restrict__ w2h,
    int nqk4, int nw4) {
  int i = blockIdx.x * 256 + threadIdx.x;
  if (i >= 2 * nqk4 + 2 * nw4) return;
  const float* src;
  unsigned short* dst;
  int j = i;
  if (j < nqk4) { src = Q; dst = qh; }
  else if ((j -= nqk4) < nqk4) { src = Km; dst = kh; }
  else if ((j -= nqk4) < nw4) { src = W1; dst = w1h; }
  else { j -= nw4; src = W2; dst = w2h; }
  f32x4 v = ((const f32x4*)src)[j];
  us4 r;
#pragma unroll
  for (int k = 0; k < 4; ++k) r[k] = f2h(v[k]);
  ((us4*)dst)[j] = r;
}

// ctx16 = f2h(shardA + shardB)   (vectorized x4)
__global__ __launch_bounds__(256) void combine2_cvt(const f32x4* __restrict__ a,
                                                    const f32x4* __restrict__ b,
                                                    us4* __restrict__ o, int n4) {
  int i = blockIdx.x * 256 + threadIdx.x;
  if (i < n4) {
    f32x4 va = a[i], vb = b[i];
    us4 r;
#pragma unroll
    for (int j = 0; j < 4; ++j) r[j] = f2h(va[j] + vb[j]);
    o[i] = r;
  }
}

// out = shardA + shardB + bias[col]   (vectorized x4; d4 = D/4)
__global__ __launch_bounds__(256) void combine2_bias(const f32x4* __restrict__ a,
                                                     const f32x4* __restrict__ b,
                                                     const float* __restrict__ bias,
                                                     f32x4* __restrict__ o, int n4, int d4) {
  int i = blockIdx.x * 256 + threadIdx.x;
  if (i < n4) {
    f32x4 va = a[i], vb = b[i];
    const int c = (i % d4) * 4;
    f32x4 r;
#pragma unroll
    for (int j = 0; j < 4; ++j) r[j] = va[j] + vb[j] + bias[c + j];
    o[i] = r;
  }
}

// V [8192 x 768] fp32 -> vT [768 x 8192] fp16
__global__ __launch_bounds__(256) void vt_kernel(const float* __restrict__ V,
                                                 unsigned short* __restrict__ vT) {
  __shared__ float t[32][33];
  const int bx = blockIdx.x, by = blockIdx.y;
  const int x = threadIdx.x, y = threadIdx.y;
#pragma unroll
  for (int r = 0; r < 4; ++r)
    t[y + r * 8][x] = V[(size_t)(by * 32 + y + r * 8) * 768 + bx * 32 + x];
  __syncthreads();
#pragma unroll
  for (int r = 0; r < 4; ++r)
    vT[(size_t)(bx * 32 + y + r * 8) * 8192 + by * 32 + x] = f2h(t[x][y + r * 8]);
}

// ---------------------------------------------------------------------------
extern "C" void kernel_launch(void* const* d_in, const int* in_sizes, int n_in,
                              void* d_out, int out_size, void* d_ws, size_t ws_size,
                              hipStream_t stream) {
  const int N = 8192, D = 768, DFF = 2048;
  const float* Q  = (const float*)d_in[0];
  const float* Km = (const float*)d_in[1];
  const float* V  = (const float*)d_in[2];
  const float* W1 = (const float*)d_in[3];
  const float* b1 = (const float*)d_in[4];
  const float* W2 = (const float*)d_in[5];
  const float* b2 = (const float*)d_in[6];

  // Workspace layout — byte-identical to R6 (254.8 MB total, crash-safe).
  char* w = (char*)d_ws;
  size_t off = 0;
  auto take = [&](size_t bytes) { void* p = w + off; off += bytes; return p; };
  unsigned short* qh   = (unsigned short*)take((size_t)N * D * 2);
  unsigned short* kh   = (unsigned short*)take((size_t)N * D * 2);
  unsigned short* vT   = (unsigned short*)take((size_t)N * D * 2);
  unsigned short* ctx16= (unsigned short*)take((size_t)N * D * 2);
  float*          ctx32= (float*)take((size_t)N * D * 4);
  unsigned short* hb   = (unsigned short*)take((size_t)N * DFF * 2);
  unsigned short* w1h  = (unsigned short*)take((size_t)DFF * D * 2);
  unsigned short* w2h  = (unsigned short*)take((size_t)D * DFF * 2);
  float*          stm  = (float*)take((size_t)64 * N * 4);
  float*          stl  = (float*)take((size_t)64 * N * 4);
  unsigned short* alp  = (unsigned short*)take((size_t)64 * N * 2);  // [tile][row]
  unsigned short* Pp   = (unsigned short*)take((size_t)N * N * 2);   // P' fp16, 128 MB
  // Aliases (no new allocation):
  //  ctxsh: PV fp32 shards x2 = 50.3 MB over ctx32(25.2) + first 25.1 MB of hb
  //         (hb written only later by FFN1, after combine2_cvt consumed shards)
  //  osh:   FFN2 fp32 shards x2 = 50.3 MB over Pp (dead after PV)
  float* ctxsh = ctx32;
  float* osh   = (float*)Pp;
  (void)ws_size;

  prep4<<<((2 * N * D + 2 * DFF * D) / 4 + 255) / 256, 256, 0, stream>>>(
      Q, Km, W1, W2, qh, kh, w1h, w2h, N * D / 4, DFF * D / 4);
  vt_kernel<<<dim3(D / 32, N / 32), dim3(32, 8), 0, stream>>>(V, vT);

  {  // QK^T 256^2 8-phase with fused exp + per-(row,128-tile) stats
    hipFuncSetAttribute((const void*)qk256,
                        hipFuncAttributeMaxDynamicSharedMemorySize, 131072);
    qk256<<<(N / 256) * (N / 256), 512, 131072, stream>>>(
        qh, kh, Pp, stm, stl, N, D, D, D, N);
  }
  combine_alpha<<<N / 4, 256, 0, stream>>>(stm, stl, alp, 64, N);

  {  // ctx shards = (alphaT .* P') . V — 256x192, sl=2, grid 256, shard store
    const int nt = D / 192, mt = N / 256, sl = 2;   // 4 x 32 x 2 = 256 blocks
    constexpr int BUFSZ = 32768 + 192 * 128;
    const int smem_sz = 2 * BUFSZ + ((N / 2) >> 7) * 256 * 2;  // 131072
    hipFuncSetAttribute((const void*)gemm256<192, 1, false, false, true, true>,
                        hipFuncAttributeMaxDynamicSharedMemorySize, smem_sz);
    gemm256<192, 1, false, false, true, true><<<nt * mt * sl, 512, smem_sz, stream>>>(
        Pp, vT, ctxsh, nullptr, alp, N,
        N / sl, N, N, D, nt, mt, sl);
  }
  combine2_cvt<<<(N * D / 4 + 255) / 256, 256, 0, stream>>>(
      (const f32x4*)ctxsh, (const f32x4*)(ctxsh + (size_t)N * D), (us4*)ctx16, N * D / 4);

  {  // h = relu(ctx . W1^T + b1)  fp16 — 256x256, grid 256 (verified R3)
    const int nt = DFF / 256, mt = N / 256;
    hipFuncSetAttribute((const void*)gemm256<256, 0, true, true, false, true>,
                        hipFuncAttributeMaxDynamicSharedMemorySize, 131072);
    gemm256<256, 0, true, true, false, true><<<nt * mt, 512, 131072, stream>>>(
        ctx16, w1h, hb, b1, nullptr, N,
        D, D, D, DFF, nt, mt, 1);
  }
  {  // out shards = h . W2^T — 256x192, sl=2, grid 256, shard store into Pp
    const int nt = D / 192, mt = N / 256, sl = 2;
    constexpr int BUFSZ = 32768 + 192 * 128;
    hipFuncSetAttribute((const void*)gemm256<192, 1, false, false, false, true>,
                        hipFuncAttributeMaxDynamicSharedMemorySize, 2 * BUFSZ);
    gemm256<192, 1, false, false, false, true><<<nt * mt * sl, 512, 2 * BUFSZ, stream>>>(
        hb, w2h, osh, nullptr, nullptr, N,
        DFF / sl, DFF, DFF, D, nt, mt, sl);
  }
  combine2_bias<<<(N * D / 4 + 255) / 256, 256, 0, stream>>>(
      (const f32x4*)osh, (const f32x4*)(osh + (size_t)N * D), b2,
      (f32x4*)d_out, N * D / 4, D / 4);
}